// Round 1
// baseline (978.625 us; speedup 1.0000x reference)
//
#include <hip/hip_runtime.h>
#include <hip/hip_bf16.h>

// GAT 2-layer forward, fp32. N=50000 nodes, E=800000 edges + N self loops.
// Layer1: IN=128 -> 4 heads x 64 (concat 256), ReLU.
// Layer2: 256 -> 1 head x 128, ReLU.

#define NEG_SLOPE 0.2f

// ---------------- CSR build ----------------

__global__ void count_kernel(const int* __restrict__ ei, int E, int N, int* __restrict__ cnt) {
    int e = blockIdx.x * blockDim.x + threadIdx.x;
    int Etot = E + N;
    if (e >= Etot) return;
    int d = (e < E) ? ei[E + e] : (e - E);
    atomicAdd(&cnt[d], 1);
}

__global__ void scan_kernel(const int* __restrict__ cnt, int* __restrict__ row_start,
                            int* __restrict__ cursor, int N) {
    const int T = 1024;
    int tid = threadIdx.x;
    int per = (N + T - 1) / T;
    int start = tid * per;
    int end = start + per; if (end > N) end = N;
    int sum = 0;
    for (int i = start; i < end; ++i) sum += cnt[i];
    __shared__ int sm[T];
    sm[tid] = sum;
    __syncthreads();
    // Hillis-Steele inclusive scan
    for (int off = 1; off < T; off <<= 1) {
        int v = (tid >= off) ? sm[tid - off] : 0;
        __syncthreads();
        sm[tid] += v;
        __syncthreads();
    }
    int excl = sm[tid] - sum;
    int run = excl;
    for (int i = start; i < end; ++i) {
        row_start[i] = run;
        cursor[i] = run;
        run += cnt[i];
    }
    if (tid == 0) row_start[N] = sm[T - 1];
}

__global__ void fill_kernel(const int* __restrict__ ei, int E, int N, int* __restrict__ cursor,
                            int* __restrict__ csr_src, int* __restrict__ csr_eid) {
    int e = blockIdx.x * blockDim.x + threadIdx.x;
    int Etot = E + N;
    if (e >= Etot) return;
    int s, d;
    if (e < E) { s = ei[e]; d = ei[E + e]; } else { s = e - E; d = s; }
    int pos = atomicAdd(&cursor[d], 1);
    csr_src[pos] = s;
    csr_eid[pos] = e;
}

// ---------------- fp32 tiled GEMM: C[M,N] = A[M,K] @ B[K,N] ----------------

__global__ __launch_bounds__(256) void sgemm(int M, int N, int K,
                                             const float* __restrict__ A,
                                             const float* __restrict__ B,
                                             float* __restrict__ C) {
    constexpr int BM = 64, BN = 64, BK = 16, TM = 4, TN = 4;
    __shared__ float As[BK][BM];   // transposed A tile
    __shared__ float Bs[BK][BN];
    const int tid = threadIdx.x;
    const int trow = tid >> 4;          // 0..15
    const int tcol = tid & 15;          // 0..15
    const int rowBase = blockIdx.x * BM;
    const int colBase = blockIdx.y * BN;

    const int aRow = tid >> 2;          // 0..63
    const int aCol = (tid & 3) << 2;    // 0,4,8,12
    const int bRow = tid >> 4;          // 0..15
    const int bCol = (tid & 15) << 2;   // 0..60

    float acc[TM][TN] = {};

    for (int k0 = 0; k0 < K; k0 += BK) {
        float4 av = make_float4(0.f, 0.f, 0.f, 0.f);
        int gr = rowBase + aRow;
        if (gr < M) av = *(const float4*)(A + (size_t)gr * K + k0 + aCol);
        As[aCol + 0][aRow] = av.x;
        As[aCol + 1][aRow] = av.y;
        As[aCol + 2][aRow] = av.z;
        As[aCol + 3][aRow] = av.w;
        float4 bv = *(const float4*)(B + (size_t)(k0 + bRow) * N + colBase + bCol);
        *(float4*)(&Bs[bRow][bCol]) = bv;
        __syncthreads();
#pragma unroll
        for (int kk = 0; kk < BK; ++kk) {
            float a[TM], b[TN];
#pragma unroll
            for (int i = 0; i < TM; ++i) a[i] = As[kk][trow * TM + i];
#pragma unroll
            for (int j = 0; j < TN; ++j) b[j] = Bs[kk][tcol * TN + j];
#pragma unroll
            for (int i = 0; i < TM; ++i)
#pragma unroll
                for (int j = 0; j < TN; ++j) acc[i][j] += a[i] * b[j];
        }
        __syncthreads();
    }
#pragma unroll
    for (int i = 0; i < TM; ++i) {
        int gr = rowBase + trow * TM + i;
        if (gr < M) {
            float4 v = make_float4(acc[i][0], acc[i][1], acc[i][2], acc[i][3]);
            *(float4*)(C + (size_t)gr * N + colBase + tcol * TN) = v;
        }
    }
}

// ---------------- attention dots: a_s[n,h] = sum_c h[n,h,c]*att_s[h,c] ----------------
// block = H*C threads, one block per node

__global__ void att_dots(const float* __restrict__ h, const float* __restrict__ att_s,
                         const float* __restrict__ att_d, float* __restrict__ as_,
                         float* __restrict__ ad_, int H, int C) {
    int n = blockIdx.x;
    int t = threadIdx.x;              // 0..H*C-1
    int HC = blockDim.x;
    int c = t & (C - 1);              // C is power of two
    extern __shared__ float sm2[];
    float* ss = sm2;
    float* sd = sm2 + HC;
    float v = h[(size_t)n * HC + t];
    ss[t] = v * att_s[t];
    sd[t] = v * att_d[t];
    __syncthreads();
    for (int s = C >> 1; s > 0; s >>= 1) {
        if (c < s) { ss[t] += ss[t + s]; sd[t] += sd[t + s]; }
        __syncthreads();
    }
    if (c == 0) {
        int head = t / C;
        as_[n * H + head] = ss[t];
        ad_[n * H + head] = sd[t];
    }
}

// ---------------- edge pass: expE[e,h] = exp(leaky_relu(as[src]+ad[dst])), denom += ----------------

__global__ void edge_pass(const int* __restrict__ ei, int E, int N,
                          const float* __restrict__ as_, const float* __restrict__ ad_,
                          float* __restrict__ expE, float* __restrict__ denom, int H) {
    int e = blockIdx.x * blockDim.x + threadIdx.x;
    int Etot = E + N;
    if (e >= Etot) return;
    int s, d;
    if (e < E) { s = ei[e]; d = ei[E + e]; } else { s = e - E; d = s; }
    for (int h = 0; h < H; ++h) {
        float v = as_[s * H + h] + ad_[d * H + h];
        v = (v > 0.f) ? v : NEG_SLOPE * v;
        float w = __expf(v);
        expE[(size_t)e * H + h] = w;
        atomicAdd(&denom[d * H + h], w);
    }
}

// ---------------- aggregate: out[n,t] = relu(bias[t] + sum_e alpha*h[src,t]) ----------------
// block = H*C threads, one block per dst node

__global__ void aggregate(const int* __restrict__ row_start, const int* __restrict__ csr_src,
                          const int* __restrict__ csr_eid, const float* __restrict__ h,
                          const float* __restrict__ expE, const float* __restrict__ denom,
                          const float* __restrict__ bias, float* __restrict__ out,
                          int H, int C) {
    int n = blockIdx.x;
    int t = threadIdx.x;
    int HC = blockDim.x;
    int head = t / C;
    int s0 = row_start[n], s1 = row_start[n + 1];
    float acc = 0.f;
    for (int p = s0; p < s1; ++p) {
        int src = csr_src[p];
        int e = csr_eid[p];
        float w = expE[(size_t)e * H + head];
        acc += w * h[(size_t)src * HC + t];
    }
    float dinv = 1.0f / (denom[n * H + head] + 1e-16f);
    float v = acc * dinv + bias[t];
    out[(size_t)n * HC + t] = (v > 0.f) ? v : 0.f;
}

extern "C" void kernel_launch(void* const* d_in, const int* in_sizes, int n_in,
                              void* d_out, int out_size, void* d_ws, size_t ws_size,
                              hipStream_t stream) {
    const float* x      = (const float*)d_in[0];
    const int*   ei     = (const int*)d_in[1];
    const float* W1     = (const float*)d_in[2];
    const float* att_s1 = (const float*)d_in[3];
    const float* att_d1 = (const float*)d_in[4];
    const float* b1     = (const float*)d_in[5];
    const float* W2     = (const float*)d_in[6];
    const float* att_s2 = (const float*)d_in[7];
    const float* att_d2 = (const float*)d_in[8];
    const float* b2     = (const float*)d_in[9];
    float* out = (float*)d_out;

    const int N_ = in_sizes[0] / 128;   // 50000
    const int E_ = in_sizes[1] / 2;     // 800000
    const int Etot = E_ + N_;           // 850000

    // workspace layout (floats)
    float* ws    = (float*)d_ws;
    float* h1    = ws;                     // N*256 (reused as h2 = N*128 in layer 2)
    float* x2    = h1 + (size_t)N_ * 256;  // N*256
    float* expE1 = x2 + (size_t)N_ * 256;  // Etot*4
    float* as1   = expE1 + (size_t)Etot * 4;  // N*4
    float* ad1   = as1 + (size_t)N_ * 4;
    float* den1  = ad1 + (size_t)N_ * 4;
    float* as2   = den1 + (size_t)N_ * 4;     // N
    float* ad2   = as2 + N_;
    float* den2  = ad2 + N_;
    float* expE2 = den2 + N_;                 // Etot
    int* cnt       = (int*)(expE2 + Etot);    // N
    int* row_start = cnt + N_;                // N+1
    int* cursor    = row_start + (N_ + 1);    // N
    int* csr_src   = cursor + N_;             // Etot
    int* csr_eid   = csr_src + Etot;          // Etot

    hipMemsetAsync(cnt,  0, (size_t)N_ * 4, stream);
    hipMemsetAsync(den1, 0, (size_t)N_ * 4 * 4, stream);
    hipMemsetAsync(den2, 0, (size_t)N_ * 4, stream);

    int eb = (Etot + 255) / 256;
    count_kernel<<<eb, 256, 0, stream>>>(ei, E_, N_, cnt);
    scan_kernel<<<1, 1024, 0, stream>>>(cnt, row_start, cursor, N_);
    fill_kernel<<<eb, 256, 0, stream>>>(ei, E_, N_, cursor, csr_src, csr_eid);

    // ---- layer 1: 128 -> 4x64 ----
    dim3 g1((N_ + 63) / 64, 256 / 64);
    sgemm<<<g1, 256, 0, stream>>>(N_, 256, 128, x, W1, h1);
    att_dots<<<N_, 256, 2 * 256 * sizeof(float), stream>>>(h1, att_s1, att_d1, as1, ad1, 4, 64);
    edge_pass<<<eb, 256, 0, stream>>>(ei, E_, N_, as1, ad1, expE1, den1, 4);
    aggregate<<<N_, 256, 0, stream>>>(row_start, csr_src, csr_eid, h1, expE1, den1, b1, x2, 4, 64);

    // ---- layer 2: 256 -> 1x128 ----
    float* h2 = h1;  // reuse
    dim3 g2((N_ + 63) / 64, 128 / 64);
    sgemm<<<g2, 256, 0, stream>>>(N_, 128, 256, x2, W2, h2);
    att_dots<<<N_, 128, 2 * 128 * sizeof(float), stream>>>(h2, att_s2, att_d2, as2, ad2, 1, 128);
    edge_pass<<<eb, 256, 0, stream>>>(ei, E_, N_, as2, ad2, expE2, den2, 1);
    aggregate<<<N_, 128, 0, stream>>>(row_start, csr_src, csr_eid, h2, expE2, den2, b2, out, 1, 128);

    (void)n_in; (void)out_size; (void)ws_size;
}

// Round 2
// 637.767 us; speedup vs baseline: 1.5345x; 1.5345x over previous
//
#include <hip/hip_runtime.h>
#include <hip/hip_bf16.h>

// GAT 2-layer forward, fp32. N=50000 nodes, E=800000 edges + N self loops.
// Layer1: IN=128 -> 4 heads x 64 (concat 256), ReLU.
// Layer2: 256 -> 1 head x 128, ReLU.
// R1: fused CSR-order edge-softmax + aggregation (no expE array, no denom
// atomics, no edge_pass kernels); one wave per node, float4/float2 row loads,
// 4-edge unroll for MLP.

#define NEG_SLOPE 0.2f

// ---------------- CSR build ----------------

__global__ void count_kernel(const int* __restrict__ ei, int E, int N, int* __restrict__ cnt) {
    int e = blockIdx.x * blockDim.x + threadIdx.x;
    int Etot = E + N;
    if (e >= Etot) return;
    int d = (e < E) ? ei[E + e] : (e - E);
    atomicAdd(&cnt[d], 1);
}

__global__ void scan_kernel(const int* __restrict__ cnt, int* __restrict__ row_start,
                            int* __restrict__ cursor, int N) {
    const int T = 1024;
    int tid = threadIdx.x;
    int per = (N + T - 1) / T;
    int start = tid * per;
    int end = start + per; if (end > N) end = N;
    int sum = 0;
    for (int i = start; i < end; ++i) sum += cnt[i];
    __shared__ int sm[T];
    sm[tid] = sum;
    __syncthreads();
    for (int off = 1; off < T; off <<= 1) {
        int v = (tid >= off) ? sm[tid - off] : 0;
        __syncthreads();
        sm[tid] += v;
        __syncthreads();
    }
    int excl = sm[tid] - sum;
    int run = excl;
    for (int i = start; i < end; ++i) {
        row_start[i] = run;
        cursor[i] = run;
        run += cnt[i];
    }
    if (tid == 0) row_start[N] = sm[T - 1];
}

__global__ void fill_kernel(const int* __restrict__ ei, int E, int N, int* __restrict__ cursor,
                            int* __restrict__ csr_src) {
    int e = blockIdx.x * blockDim.x + threadIdx.x;
    int Etot = E + N;
    if (e >= Etot) return;
    int s, d;
    if (e < E) { s = ei[e]; d = ei[E + e]; } else { s = e - E; d = s; }
    int pos = atomicAdd(&cursor[d], 1);
    csr_src[pos] = s;
}

// ---------------- fp32 tiled GEMM: C[M,N] = A[M,K] @ B[K,N] ----------------

__global__ __launch_bounds__(256) void sgemm(int M, int N, int K,
                                             const float* __restrict__ A,
                                             const float* __restrict__ B,
                                             float* __restrict__ C) {
    constexpr int BM = 64, BN = 64, BK = 16, TM = 4, TN = 4;
    __shared__ float As[BK][BM];   // transposed A tile
    __shared__ float Bs[BK][BN];
    const int tid = threadIdx.x;
    const int trow = tid >> 4;          // 0..15
    const int tcol = tid & 15;          // 0..15
    const int rowBase = blockIdx.x * BM;
    const int colBase = blockIdx.y * BN;

    const int aRow = tid >> 2;          // 0..63
    const int aCol = (tid & 3) << 2;    // 0,4,8,12
    const int bRow = tid >> 4;          // 0..15
    const int bCol = (tid & 15) << 2;   // 0..60

    float acc[TM][TN] = {};

    for (int k0 = 0; k0 < K; k0 += BK) {
        float4 av = make_float4(0.f, 0.f, 0.f, 0.f);
        int gr = rowBase + aRow;
        if (gr < M) av = *(const float4*)(A + (size_t)gr * K + k0 + aCol);
        As[aCol + 0][aRow] = av.x;
        As[aCol + 1][aRow] = av.y;
        As[aCol + 2][aRow] = av.z;
        As[aCol + 3][aRow] = av.w;
        float4 bv = *(const float4*)(B + (size_t)(k0 + bRow) * N + colBase + bCol);
        *(float4*)(&Bs[bRow][bCol]) = bv;
        __syncthreads();
#pragma unroll
        for (int kk = 0; kk < BK; ++kk) {
            float a[TM], b[TN];
#pragma unroll
            for (int i = 0; i < TM; ++i) a[i] = As[kk][trow * TM + i];
#pragma unroll
            for (int j = 0; j < TN; ++j) b[j] = Bs[kk][tcol * TN + j];
#pragma unroll
            for (int i = 0; i < TM; ++i)
#pragma unroll
                for (int j = 0; j < TN; ++j) acc[i][j] += a[i] * b[j];
        }
        __syncthreads();
    }
#pragma unroll
    for (int i = 0; i < TM; ++i) {
        int gr = rowBase + trow * TM + i;
        if (gr < M) {
            float4 v = make_float4(acc[i][0], acc[i][1], acc[i][2], acc[i][3]);
            *(float4*)(C + (size_t)gr * N + colBase + tcol * TN) = v;
        }
    }
}

// ---------------- attention dots: a_s[n,h] = sum_c h[n,h,c]*att_s[h,c] ----------------

__global__ void att_dots(const float* __restrict__ h, const float* __restrict__ att_s,
                         const float* __restrict__ att_d, float* __restrict__ as_,
                         float* __restrict__ ad_, int H, int C) {
    int n = blockIdx.x;
    int t = threadIdx.x;              // 0..H*C-1
    int HC = blockDim.x;
    int c = t & (C - 1);              // C is power of two
    extern __shared__ float sm2[];
    float* ss = sm2;
    float* sd = sm2 + HC;
    float v = h[(size_t)n * HC + t];
    ss[t] = v * att_s[t];
    sd[t] = v * att_d[t];
    __syncthreads();
    for (int s = C >> 1; s > 0; s >>= 1) {
        if (c < s) { ss[t] += ss[t + s]; sd[t] += sd[t + s]; }
        __syncthreads();
    }
    if (c == 0) {
        int head = t / C;
        as_[n * H + head] = ss[t];
        ad_[n * H + head] = sd[t];
    }
}

// ---------------- fused CSR softmax + aggregate ----------------
// One wave (64 threads) per dst node. THREAD t owns channels [t*VEC, t*VEC+VEC).
// Per edge: w = exp(leaky_relu(as[src]+ad[n])) computed inline (denominator
// accumulated redundantly per lane within a head group -- identical values).

template<int VEC> __device__ inline void loadVec(float* dst, const float* src);
template<> __device__ inline void loadVec<4>(float* dst, const float* src) {
    *(float4*)dst = *(const float4*)src;
}
template<> __device__ inline void loadVec<2>(float* dst, const float* src) {
    *(float2*)dst = *(const float2*)src;
}

template<int HC, int H, int VEC>
__global__ __launch_bounds__(64) void fused_agg(const int* __restrict__ row_start,
                                                const int* __restrict__ csr_src,
                                                const float* __restrict__ h,
                                                const float* __restrict__ as_,
                                                const float* __restrict__ ad_,
                                                const float* __restrict__ bias,
                                                float* __restrict__ out) {
    constexpr int C = HC / H;
    const int n = blockIdx.x;
    const int t = threadIdx.x;           // 0..63
    const int c0 = t * VEC;
    const int head = c0 / C;
    const int s0 = row_start[n], s1 = row_start[n + 1];
    const float adv = ad_[n * H + head];
    float acc[VEC] = {};
    float den = 0.f;
    int p = s0;
    for (; p + 4 <= s1; p += 4) {
        int src0 = csr_src[p + 0];
        int src1 = csr_src[p + 1];
        int src2 = csr_src[p + 2];
        int src3 = csr_src[p + 3];
        float as0 = as_[src0 * H + head];
        float as1v = as_[src1 * H + head];
        float as2 = as_[src2 * H + head];
        float as3 = as_[src3 * H + head];
        float v0[VEC], v1[VEC], v2[VEC], v3[VEC];
        loadVec<VEC>(v0, h + (size_t)src0 * HC + c0);
        loadVec<VEC>(v1, h + (size_t)src1 * HC + c0);
        loadVec<VEC>(v2, h + (size_t)src2 * HC + c0);
        loadVec<VEC>(v3, h + (size_t)src3 * HC + c0);
        float e0 = as0 + adv;  e0 = e0 > 0.f ? e0 : NEG_SLOPE * e0;
        float e1 = as1v + adv; e1 = e1 > 0.f ? e1 : NEG_SLOPE * e1;
        float e2 = as2 + adv;  e2 = e2 > 0.f ? e2 : NEG_SLOPE * e2;
        float e3 = as3 + adv;  e3 = e3 > 0.f ? e3 : NEG_SLOPE * e3;
        float w0 = __expf(e0), w1 = __expf(e1), w2 = __expf(e2), w3 = __expf(e3);
        den += (w0 + w1) + (w2 + w3);
#pragma unroll
        for (int i = 0; i < VEC; ++i)
            acc[i] += w0 * v0[i] + w1 * v1[i] + w2 * v2[i] + w3 * v3[i];
    }
    for (; p < s1; ++p) {
        int src = csr_src[p];
        float e = as_[src * H + head] + adv;
        e = e > 0.f ? e : NEG_SLOPE * e;
        float w = __expf(e);
        float v[VEC];
        loadVec<VEC>(v, h + (size_t)src * HC + c0);
        den += w;
#pragma unroll
        for (int i = 0; i < VEC; ++i) acc[i] += w * v[i];
    }
    float dinv = 1.0f / (den + 1e-16f);
#pragma unroll
    for (int i = 0; i < VEC; ++i) {
        float o = acc[i] * dinv + bias[c0 + i];
        out[(size_t)n * HC + c0 + i] = o > 0.f ? o : 0.f;
    }
}

extern "C" void kernel_launch(void* const* d_in, const int* in_sizes, int n_in,
                              void* d_out, int out_size, void* d_ws, size_t ws_size,
                              hipStream_t stream) {
    const float* x      = (const float*)d_in[0];
    const int*   ei     = (const int*)d_in[1];
    const float* W1     = (const float*)d_in[2];
    const float* att_s1 = (const float*)d_in[3];
    const float* att_d1 = (const float*)d_in[4];
    const float* b1     = (const float*)d_in[5];
    const float* W2     = (const float*)d_in[6];
    const float* att_s2 = (const float*)d_in[7];
    const float* att_d2 = (const float*)d_in[8];
    const float* b2     = (const float*)d_in[9];
    float* out = (float*)d_out;

    const int N_ = in_sizes[0] / 128;   // 50000
    const int E_ = in_sizes[1] / 2;     // 800000
    const int Etot = E_ + N_;           // 850000

    // workspace layout (floats)
    float* ws  = (float*)d_ws;
    float* h1  = ws;                          // N*256 (reused as h2 in layer 2)
    float* x2  = h1 + (size_t)N_ * 256;       // N*256
    float* as1 = x2 + (size_t)N_ * 256;       // N*4
    float* ad1 = as1 + (size_t)N_ * 4;        // N*4
    float* as2 = ad1 + (size_t)N_ * 4;        // N
    float* ad2 = as2 + N_;                    // N
    int* cnt       = (int*)(ad2 + N_);        // N
    int* row_start = cnt + N_;                // N+1
    int* cursor    = row_start + (N_ + 1);    // N
    int* csr_src   = cursor + N_;             // Etot

    hipMemsetAsync(cnt, 0, (size_t)N_ * 4, stream);

    int eb = (Etot + 255) / 256;
    count_kernel<<<eb, 256, 0, stream>>>(ei, E_, N_, cnt);
    scan_kernel<<<1, 1024, 0, stream>>>(cnt, row_start, cursor, N_);
    fill_kernel<<<eb, 256, 0, stream>>>(ei, E_, N_, cursor, csr_src);

    // ---- layer 1: 128 -> 4x64 ----
    dim3 g1((N_ + 63) / 64, 256 / 64);
    sgemm<<<g1, 256, 0, stream>>>(N_, 256, 128, x, W1, h1);
    att_dots<<<N_, 256, 2 * 256 * sizeof(float), stream>>>(h1, att_s1, att_d1, as1, ad1, 4, 64);
    fused_agg<256, 4, 4><<<N_, 64, 0, stream>>>(row_start, csr_src, h1, as1, ad1, b1, x2);

    // ---- layer 2: 256 -> 1x128 ----
    float* h2 = h1;  // reuse
    dim3 g2((N_ + 63) / 64, 128 / 64);
    sgemm<<<g2, 256, 0, stream>>>(N_, 128, 256, x2, W2, h2);
    att_dots<<<N_, 128, 2 * 128 * sizeof(float), stream>>>(h2, att_s2, att_d2, as2, ad2, 1, 128);
    fused_agg<128, 1, 2><<<N_, 64, 0, stream>>>(row_start, csr_src, h2, as2, ad2, b2, out);

    (void)n_in; (void)out_size; (void)ws_size;
}

// Round 3
// 617.616 us; speedup vs baseline: 1.5845x; 1.0326x over previous
//
#include <hip/hip_runtime.h>
#include <hip/hip_bf16.h>

// GAT 2-layer forward. N=50000, E=800000 (+N self loops).
// L1: 128 -> 4x64 concat 256, ReLU.  L2: 256 -> 128, ReLU.
// R1: fused CSR softmax+aggregate (one wave/node).
// R2: GEMMs via bf16 MFMA with hi/lo split precision (Ah*Bh + Ah*Bl + Al*Bh
//     ~ fp32 accuracy); B pre-packed to fragment lane layout; fused_agg L1
//     emits x2 directly as bf16 hi/lo.

#define NEG_SLOPE 0.2f

typedef __attribute__((ext_vector_type(8))) short bf16x8;   // 8 bf16 = 4 VGPRs
typedef __attribute__((ext_vector_type(4))) float f32x4;

__device__ inline unsigned short f2bf(float f) {            // RNE f32 -> bf16
    unsigned int u = __float_as_uint(f);
    u += 0x7fff + ((u >> 16) & 1);
    return (unsigned short)(u >> 16);
}
__device__ inline float bf2f(unsigned short h) {
    return __uint_as_float(((unsigned int)h) << 16);
}

// ---------------- CSR build ----------------

__global__ void count_kernel(const int* __restrict__ ei, int E, int N, int* __restrict__ cnt) {
    int e = blockIdx.x * blockDim.x + threadIdx.x;
    int Etot = E + N;
    if (e >= Etot) return;
    int d = (e < E) ? ei[E + e] : (e - E);
    atomicAdd(&cnt[d], 1);
}

__global__ void scan_kernel(const int* __restrict__ cnt, int* __restrict__ row_start,
                            int* __restrict__ cursor, int N) {
    const int T = 1024;
    int tid = threadIdx.x;
    int per = (N + T - 1) / T;
    int start = tid * per;
    int end = start + per; if (end > N) end = N;
    int sum = 0;
    for (int i = start; i < end; ++i) sum += cnt[i];
    __shared__ int sm[T];
    sm[tid] = sum;
    __syncthreads();
    for (int off = 1; off < T; off <<= 1) {
        int v = (tid >= off) ? sm[tid - off] : 0;
        __syncthreads();
        sm[tid] += v;
        __syncthreads();
    }
    int excl = sm[tid] - sum;
    int run = excl;
    for (int i = start; i < end; ++i) {
        row_start[i] = run;
        cursor[i] = run;
        run += cnt[i];
    }
    if (tid == 0) row_start[N] = sm[T - 1];
}

__global__ void fill_kernel(const int* __restrict__ ei, int E, int N, int* __restrict__ cursor,
                            int* __restrict__ csr_src) {
    int e = blockIdx.x * blockDim.x + threadIdx.x;
    int Etot = E + N;
    if (e >= Etot) return;
    int s, d;
    if (e < E) { s = ei[e]; d = ei[E + e]; } else { s = e - E; d = s; }
    int pos = atomicAdd(&cursor[d], 1);
    csr_src[pos] = s;
}

// ---------------- fp32 -> bf16 hi/lo split ----------------

__global__ void split_kernel(const float* __restrict__ in, unsigned short* __restrict__ hi,
                             unsigned short* __restrict__ lo, int n) {
    int i = blockIdx.x * blockDim.x + threadIdx.x;
    if (i >= n) return;
    float v = in[i];
    unsigned short h = f2bf(v);
    hi[i] = h;
    lo[i] = f2bf(v - bf2f(h));
}

// ---------------- pack W into MFMA B-fragment layout ----------------
// B-frag (16x16x32): lane l holds B[k0 + (l>>4)*8 + j][n0 + (l&15)], j=0..7.
// Bp index = ((ct*(K/32) + ks)*64 + lane)*8 + j  -> 16B contiguous per lane.

__global__ void pack_w(const float* __restrict__ W, unsigned short* __restrict__ bph,
                       unsigned short* __restrict__ bpl, int K, int N) {
    int tid = blockIdx.x * blockDim.x + threadIdx.x;
    if (tid >= K * N) return;
    int k = tid / N, n = tid - k * N;
    int ks = k >> 5, k5 = k & 31, quad = k5 >> 3, j = k5 & 7;
    int ct = n >> 4;
    int lane = quad * 16 + (n & 15);
    size_t idx = ((size_t)(ct * (K >> 5) + ks) * 64 + lane) * 8 + j;
    float w = W[tid];
    unsigned short h = f2bf(w);
    bph[idx] = h;
    bpl[idx] = f2bf(w - bf2f(h));
}

// ---------------- split-precision bf16 MFMA GEMM ----------------
// C[M,N] = (Ah+Al)[M,K] @ W[K,N], 3 products. Block = 4 waves; wave w owns
// rows [blk*128 + w*32, +32) x 64 cols (2x4 tiles of 16x16x32 MFMA).

template<int K>
__global__ __launch_bounds__(256) void mfma_gemm(int M, int N,
        const unsigned short* __restrict__ Ah, const unsigned short* __restrict__ Al,
        const unsigned short* __restrict__ Bph, const unsigned short* __restrict__ Bpl,
        float* __restrict__ C) {
    constexpr int KS = K >> 5;
    const int lane = threadIdx.x & 63;
    const int w = threadIdx.x >> 6;
    const int quad = lane >> 4;
    const int r16 = lane & 15;
    const int mBase = blockIdx.x * 128 + w * 32;
    const int nBase = blockIdx.y * 64;

    f32x4 acc[2][4];
#pragma unroll
    for (int rt = 0; rt < 2; ++rt)
#pragma unroll
        for (int ct = 0; ct < 4; ++ct) acc[rt][ct] = (f32x4){0.f, 0.f, 0.f, 0.f};

#pragma unroll
    for (int ks = 0; ks < KS; ++ks) {
        bf16x8 ahf[2], alf[2];
#pragma unroll
        for (int rt = 0; rt < 2; ++rt) {
            int row = mBase + rt * 16 + r16;
            if (row < M) {
                size_t off = (size_t)row * K + ks * 32 + quad * 8;
                ahf[rt] = *(const bf16x8*)(Ah + off);
                alf[rt] = *(const bf16x8*)(Al + off);
            } else {
                ahf[rt] = (bf16x8){0,0,0,0,0,0,0,0};
                alf[rt] = (bf16x8){0,0,0,0,0,0,0,0};
            }
        }
        bf16x8 bhf[4], blf[4];
#pragma unroll
        for (int ct = 0; ct < 4; ++ct) {
            int ctg = (nBase >> 4) + ct;
            size_t off = ((size_t)(ctg * KS + ks) * 64 + lane) * 8;
            bhf[ct] = *(const bf16x8*)(Bph + off);
            blf[ct] = *(const bf16x8*)(Bpl + off);
        }
#pragma unroll
        for (int rt = 0; rt < 2; ++rt)
#pragma unroll
            for (int ct = 0; ct < 4; ++ct) {
                acc[rt][ct] = __builtin_amdgcn_mfma_f32_16x16x32_bf16(ahf[rt], bhf[ct], acc[rt][ct], 0, 0, 0);
                acc[rt][ct] = __builtin_amdgcn_mfma_f32_16x16x32_bf16(ahf[rt], blf[ct], acc[rt][ct], 0, 0, 0);
                acc[rt][ct] = __builtin_amdgcn_mfma_f32_16x16x32_bf16(alf[rt], bhf[ct], acc[rt][ct], 0, 0, 0);
            }
    }

    // C/D layout: lane l reg r -> row = (l>>4)*4 + r, col = l&15
#pragma unroll
    for (int rt = 0; rt < 2; ++rt)
#pragma unroll
        for (int ct = 0; ct < 4; ++ct) {
            int row0 = mBase + rt * 16 + quad * 4;
            int col = nBase + ct * 16 + r16;
#pragma unroll
            for (int r = 0; r < 4; ++r) {
                int row = row0 + r;
                if (row < M) C[(size_t)row * N + col] = acc[rt][ct][r];
            }
        }
}

// ---------------- attention dots ----------------

__global__ void att_dots(const float* __restrict__ h, const float* __restrict__ att_s,
                         const float* __restrict__ att_d, float* __restrict__ as_,
                         float* __restrict__ ad_, int H, int C) {
    int n = blockIdx.x;
    int t = threadIdx.x;
    int HC = blockDim.x;
    int c = t & (C - 1);
    extern __shared__ float sm2[];
    float* ss = sm2;
    float* sd = sm2 + HC;
    float v = h[(size_t)n * HC + t];
    ss[t] = v * att_s[t];
    sd[t] = v * att_d[t];
    __syncthreads();
    for (int s = C >> 1; s > 0; s >>= 1) {
        if (c < s) { ss[t] += ss[t + s]; sd[t] += sd[t + s]; }
        __syncthreads();
    }
    if (c == 0) {
        int head = t / C;
        as_[n * H + head] = ss[t];
        ad_[n * H + head] = sd[t];
    }
}

// ---------------- fused CSR softmax + aggregate ----------------

template<int VEC> __device__ inline void loadVec(float* dst, const float* src);
template<> __device__ inline void loadVec<4>(float* dst, const float* src) {
    *(float4*)dst = *(const float4*)src;
}
template<> __device__ inline void loadVec<2>(float* dst, const float* src) {
    *(float2*)dst = *(const float2*)src;
}

template<int HC, int H, int VEC, bool BF16OUT>
__global__ __launch_bounds__(64) void fused_agg(const int* __restrict__ row_start,
                                                const int* __restrict__ csr_src,
                                                const float* __restrict__ h,
                                                const float* __restrict__ as_,
                                                const float* __restrict__ ad_,
                                                const float* __restrict__ bias,
                                                float* __restrict__ out,
                                                unsigned short* __restrict__ outh,
                                                unsigned short* __restrict__ outl) {
    constexpr int C = HC / H;
    const int n = blockIdx.x;
    const int t = threadIdx.x;
    const int c0 = t * VEC;
    const int head = c0 / C;
    const int s0 = row_start[n], s1 = row_start[n + 1];
    const float adv = ad_[n * H + head];
    float acc[VEC] = {};
    float den = 0.f;
    int p = s0;
    for (; p + 4 <= s1; p += 4) {
        int src0 = csr_src[p + 0];
        int src1 = csr_src[p + 1];
        int src2 = csr_src[p + 2];
        int src3 = csr_src[p + 3];
        float as0 = as_[src0 * H + head];
        float as1v = as_[src1 * H + head];
        float as2 = as_[src2 * H + head];
        float as3 = as_[src3 * H + head];
        float v0[VEC], v1[VEC], v2[VEC], v3[VEC];
        loadVec<VEC>(v0, h + (size_t)src0 * HC + c0);
        loadVec<VEC>(v1, h + (size_t)src1 * HC + c0);
        loadVec<VEC>(v2, h + (size_t)src2 * HC + c0);
        loadVec<VEC>(v3, h + (size_t)src3 * HC + c0);
        float e0 = as0 + adv;  e0 = e0 > 0.f ? e0 : NEG_SLOPE * e0;
        float e1 = as1v + adv; e1 = e1 > 0.f ? e1 : NEG_SLOPE * e1;
        float e2 = as2 + adv;  e2 = e2 > 0.f ? e2 : NEG_SLOPE * e2;
        float e3 = as3 + adv;  e3 = e3 > 0.f ? e3 : NEG_SLOPE * e3;
        float w0 = __expf(e0), w1 = __expf(e1), w2 = __expf(e2), w3 = __expf(e3);
        den += (w0 + w1) + (w2 + w3);
#pragma unroll
        for (int i = 0; i < VEC; ++i)
            acc[i] += w0 * v0[i] + w1 * v1[i] + w2 * v2[i] + w3 * v3[i];
    }
    for (; p < s1; ++p) {
        int src = csr_src[p];
        float e = as_[src * H + head] + adv;
        e = e > 0.f ? e : NEG_SLOPE * e;
        float w = __expf(e);
        float v[VEC];
        loadVec<VEC>(v, h + (size_t)src * HC + c0);
        den += w;
#pragma unroll
        for (int i = 0; i < VEC; ++i) acc[i] += w * v[i];
    }
    float dinv = 1.0f / (den + 1e-16f);
    float o[VEC];
#pragma unroll
    for (int i = 0; i < VEC; ++i) {
        float v = acc[i] * dinv + bias[c0 + i];
        o[i] = v > 0.f ? v : 0.f;
    }
    if (BF16OUT) {
        unsigned short hb[VEC], lb[VEC];
#pragma unroll
        for (int i = 0; i < VEC; ++i) {
            hb[i] = f2bf(o[i]);
            lb[i] = f2bf(o[i] - bf2f(hb[i]));
        }
#pragma unroll
        for (int i = 0; i < VEC; ++i) {
            outh[(size_t)n * HC + c0 + i] = hb[i];
            outl[(size_t)n * HC + c0 + i] = lb[i];
        }
    } else {
#pragma unroll
        for (int i = 0; i < VEC; ++i) out[(size_t)n * HC + c0 + i] = o[i];
    }
}

extern "C" void kernel_launch(void* const* d_in, const int* in_sizes, int n_in,
                              void* d_out, int out_size, void* d_ws, size_t ws_size,
                              hipStream_t stream) {
    const float* x      = (const float*)d_in[0];
    const int*   ei     = (const int*)d_in[1];
    const float* W1     = (const float*)d_in[2];
    const float* att_s1 = (const float*)d_in[3];
    const float* att_d1 = (const float*)d_in[4];
    const float* b1     = (const float*)d_in[5];
    const float* W2     = (const float*)d_in[6];
    const float* att_s2 = (const float*)d_in[7];
    const float* att_d2 = (const float*)d_in[8];
    const float* b2     = (const float*)d_in[9];
    float* out = (float*)d_out;

    const int N_ = in_sizes[0] / 128;   // 50000
    const int E_ = in_sizes[1] / 2;     // 800000
    const int Etot = E_ + N_;           // 850000

    // workspace layout
    float* ws = (float*)d_ws;
    float* h1 = ws;                                     // N*256 f32 (also h2)
    unsigned short* x2h = (unsigned short*)(h1 + (size_t)N_ * 256);  // N*256 bf16
    unsigned short* x2l = x2h + (size_t)N_ * 256;                    // N*256 bf16
    // x hi/lo overlay the x2 region (x dead once sgemm1 completes, before
    // fused_agg1 writes x2):
    unsigned short* xh = x2h;                           // N*128 bf16
    unsigned short* xl = x2l;                           // N*128 bf16
    unsigned short* bp1h = x2l + (size_t)N_ * 256;      // 32768
    unsigned short* bp1l = bp1h + 32768;
    unsigned short* bp2h = bp1l + 32768;
    unsigned short* bp2l = bp2h + 32768;
    float* as1 = (float*)(bp2l + 32768);                // N*4
    float* ad1 = as1 + (size_t)N_ * 4;                  // N*4
    float* as2 = ad1 + (size_t)N_ * 4;                  // N
    float* ad2 = as2 + N_;                              // N
    int* cnt       = (int*)(ad2 + N_);                  // N
    int* row_start = cnt + N_;                          // N+1
    int* cursor    = row_start + (N_ + 1);              // N
    int* csr_src   = cursor + N_;                       // Etot

    hipMemsetAsync(cnt, 0, (size_t)N_ * 4, stream);

    int eb = (Etot + 255) / 256;
    count_kernel<<<eb, 256, 0, stream>>>(ei, E_, N_, cnt);
    scan_kernel<<<1, 1024, 0, stream>>>(cnt, row_start, cursor, N_);
    fill_kernel<<<eb, 256, 0, stream>>>(ei, E_, N_, cursor, csr_src);

    // split x, pack weights
    split_kernel<<<((N_ * 128) + 255) / 256, 256, 0, stream>>>(x, xh, xl, N_ * 128);
    pack_w<<<(128 * 256 + 255) / 256, 256, 0, stream>>>(W1, bp1h, bp1l, 128, 256);
    pack_w<<<(256 * 128 + 255) / 256, 256, 0, stream>>>(W2, bp2h, bp2l, 256, 128);

    const int gx = (N_ + 127) / 128;    // 391

    // ---- layer 1: 128 -> 4x64 ----
    mfma_gemm<128><<<dim3(gx, 4), 256, 0, stream>>>(N_, 256, xh, xl, bp1h, bp1l, h1);
    att_dots<<<N_, 256, 2 * 256 * sizeof(float), stream>>>(h1, att_s1, att_d1, as1, ad1, 4, 64);
    fused_agg<256, 4, 4, true><<<N_, 64, 0, stream>>>(row_start, csr_src, h1, as1, ad1, b1,
                                                      nullptr, x2h, x2l);

    // ---- layer 2: 256 -> 1x128 ----
    float* h2 = h1;  // reuse
    mfma_gemm<256><<<dim3(gx, 2), 256, 0, stream>>>(N_, 128, x2h, x2l, bp2h, bp2l, h2);
    att_dots<<<N_, 128, 2 * 128 * sizeof(float), stream>>>(h2, att_s2, att_d2, as2, ad2, 1, 128);
    fused_agg<128, 1, 2, false><<<N_, 64, 0, stream>>>(row_start, csr_src, h2, as2, ad2, b2,
                                                       out, nullptr, nullptr);

    (void)n_in; (void)out_size; (void)ws_size;
}

// Round 4
// 523.437 us; speedup vs baseline: 1.8696x; 1.1799x over previous
//
#include <hip/hip_runtime.h>
#include <hip/hip_bf16.h>
#include <hip/hip_fp16.h>

// GAT 2-layer forward. N=50000, E=800000 (+N self loops).
// L1: 128 -> 4x64 concat 256, ReLU.  L2: 256 -> 128, ReLU.
// R1: fused CSR softmax+aggregate (one wave/node).
// R2: GEMMs via bf16 MFMA hi/lo split (Ah*Bh + Ah*Bl + Al*Bh ~ fp32).
// R3: h stored fp16 (halves gather traffic); GEMM blocks cover full N
//     (A fetched once); aggregation splits wave into HC/8-lane edge groups
//     (2-4 edges in flight x4 unroll) with shfl_xor combine.

#define NEG_SLOPE 0.2f

typedef __attribute__((ext_vector_type(8))) short s16x8;   // 8 x 16-bit = 4 VGPRs
typedef __attribute__((ext_vector_type(4))) float f32x4;

__device__ inline unsigned short f2bf(float f) {            // RNE f32 -> bf16
    unsigned int u = __float_as_uint(f);
    u += 0x7fff + ((u >> 16) & 1);
    return (unsigned short)(u >> 16);
}
__device__ inline float bf2f(unsigned short h) {
    return __uint_as_float(((unsigned int)h) << 16);
}

// 16B load of 8 fp16 -> 8 fp32
__device__ inline void loadH8(float* v, const __half* p) {
    union { s16x8 raw; __half2 h2[4]; } u;
    u.raw = *(const s16x8*)p;
#pragma unroll
    for (int i = 0; i < 4; ++i) {
        float2 f = __half22float2(u.h2[i]);
        v[2 * i] = f.x;
        v[2 * i + 1] = f.y;
    }
}

// ---------------- CSR build ----------------

__global__ void count_kernel(const int* __restrict__ ei, int E, int N, int* __restrict__ cnt) {
    int e = blockIdx.x * blockDim.x + threadIdx.x;
    int Etot = E + N;
    if (e >= Etot) return;
    int d = (e < E) ? ei[E + e] : (e - E);
    atomicAdd(&cnt[d], 1);
}

__global__ void scan_kernel(const int* __restrict__ cnt, int* __restrict__ row_start,
                            int* __restrict__ cursor, int N) {
    const int T = 1024;
    int tid = threadIdx.x;
    int per = (N + T - 1) / T;
    int start = tid * per;
    int end = start + per; if (end > N) end = N;
    int sum = 0;
    for (int i = start; i < end; ++i) sum += cnt[i];
    __shared__ int sm[T];
    sm[tid] = sum;
    __syncthreads();
    for (int off = 1; off < T; off <<= 1) {
        int v = (tid >= off) ? sm[tid - off] : 0;
        __syncthreads();
        sm[tid] += v;
        __syncthreads();
    }
    int excl = sm[tid] - sum;
    int run = excl;
    for (int i = start; i < end; ++i) {
        row_start[i] = run;
        cursor[i] = run;
        run += cnt[i];
    }
    if (tid == 0) row_start[N] = sm[T - 1];
}

__global__ void fill_kernel(const int* __restrict__ ei, int E, int N, int* __restrict__ cursor,
                            int* __restrict__ csr_src) {
    int e = blockIdx.x * blockDim.x + threadIdx.x;
    int Etot = E + N;
    if (e >= Etot) return;
    int s, d;
    if (e < E) { s = ei[e]; d = ei[E + e]; } else { s = e - E; d = s; }
    int pos = atomicAdd(&cursor[d], 1);
    csr_src[pos] = s;
}

// ---------------- fp32 -> bf16 hi/lo split ----------------

__global__ void split_kernel(const float* __restrict__ in, unsigned short* __restrict__ hi,
                             unsigned short* __restrict__ lo, int n) {
    int i = blockIdx.x * blockDim.x + threadIdx.x;
    if (i >= n) return;
    float v = in[i];
    unsigned short h = f2bf(v);
    hi[i] = h;
    lo[i] = f2bf(v - bf2f(h));
}

// ---------------- pack W into MFMA B-fragment layout ----------------
// B-frag (16x16x32): lane l holds B[k0 + (l>>4)*8 + j][n0 + (l&15)], j=0..7.

__global__ void pack_w(const float* __restrict__ W, unsigned short* __restrict__ bph,
                       unsigned short* __restrict__ bpl, int K, int N) {
    int tid = blockIdx.x * blockDim.x + threadIdx.x;
    if (tid >= K * N) return;
    int k = tid / N, n = tid - k * N;
    int ks = k >> 5, k5 = k & 31, quad = k5 >> 3, j = k5 & 7;
    int ct = n >> 4;
    int lane = quad * 16 + (n & 15);
    size_t idx = ((size_t)(ct * (K >> 5) + ks) * 64 + lane) * 8 + j;
    float w = W[tid];
    unsigned short h = f2bf(w);
    bph[idx] = h;
    bpl[idx] = f2bf(w - bf2f(h));
}

// ---------------- split-precision bf16 MFMA GEMM, fp16 output ----------------
// One block covers all NN columns (A fetched once). CW = NN/64 column-waves;
// 4/CW row-wave-groups of 32 rows each.

template<int K, int NN>
__global__ __launch_bounds__(256) void mfma_gemm(int M,
        const unsigned short* __restrict__ Ah, const unsigned short* __restrict__ Al,
        const unsigned short* __restrict__ Bph, const unsigned short* __restrict__ Bpl,
        __half* __restrict__ Hout) {
    constexpr int KS = K >> 5;
    constexpr int CW = NN / 64;            // waves across columns
    constexpr int RW = 4 / CW;             // row-wave groups per block
    const int lane = threadIdx.x & 63;
    const int w = threadIdx.x >> 6;
    const int wr = w / CW;
    const int wc = w % CW;
    const int quad = lane >> 4;
    const int r16 = lane & 15;
    const int mBase = blockIdx.x * (RW * 32) + wr * 32;
    const int nBase = wc * 64;

    f32x4 acc[2][4];
#pragma unroll
    for (int rt = 0; rt < 2; ++rt)
#pragma unroll
        for (int ct = 0; ct < 4; ++ct) acc[rt][ct] = (f32x4){0.f, 0.f, 0.f, 0.f};

#pragma unroll
    for (int ks = 0; ks < KS; ++ks) {
        s16x8 ahf[2], alf[2];
#pragma unroll
        for (int rt = 0; rt < 2; ++rt) {
            int row = mBase + rt * 16 + r16;
            if (row < M) {
                size_t off = (size_t)row * K + ks * 32 + quad * 8;
                ahf[rt] = *(const s16x8*)(Ah + off);
                alf[rt] = *(const s16x8*)(Al + off);
            } else {
                ahf[rt] = (s16x8){0,0,0,0,0,0,0,0};
                alf[rt] = (s16x8){0,0,0,0,0,0,0,0};
            }
        }
        s16x8 bhf[4], blf[4];
#pragma unroll
        for (int ct = 0; ct < 4; ++ct) {
            int ctg = (nBase >> 4) + ct;
            size_t off = ((size_t)(ctg * KS + ks) * 64 + lane) * 8;
            bhf[ct] = *(const s16x8*)(Bph + off);
            blf[ct] = *(const s16x8*)(Bpl + off);
        }
#pragma unroll
        for (int rt = 0; rt < 2; ++rt)
#pragma unroll
            for (int ct = 0; ct < 4; ++ct) {
                acc[rt][ct] = __builtin_amdgcn_mfma_f32_16x16x32_bf16(ahf[rt], bhf[ct], acc[rt][ct], 0, 0, 0);
                acc[rt][ct] = __builtin_amdgcn_mfma_f32_16x16x32_bf16(ahf[rt], blf[ct], acc[rt][ct], 0, 0, 0);
                acc[rt][ct] = __builtin_amdgcn_mfma_f32_16x16x32_bf16(alf[rt], bhf[ct], acc[rt][ct], 0, 0, 0);
            }
    }

    // C/D layout: lane l reg r -> row = (l>>4)*4 + r, col = l&15
#pragma unroll
    for (int rt = 0; rt < 2; ++rt)
#pragma unroll
        for (int ct = 0; ct < 4; ++ct) {
            int row0 = mBase + rt * 16 + quad * 4;
            int col = nBase + ct * 16 + r16;
#pragma unroll
            for (int r = 0; r < 4; ++r) {
                int row = row0 + r;
                if (row < M) Hout[(size_t)row * NN + col] = __float2half(acc[rt][ct][r]);
            }
        }
}

// ---------------- attention dots (fp16 h) ----------------

__global__ void att_dots(const __half* __restrict__ h, const float* __restrict__ att_s,
                         const float* __restrict__ att_d, float* __restrict__ as_,
                         float* __restrict__ ad_, int H, int C) {
    int n = blockIdx.x;
    int t = threadIdx.x;
    int HC = blockDim.x;
    int c = t & (C - 1);
    extern __shared__ float sm2[];
    float* ss = sm2;
    float* sd = sm2 + HC;
    float v = __half2float(h[(size_t)n * HC + t]);
    ss[t] = v * att_s[t];
    sd[t] = v * att_d[t];
    __syncthreads();
    for (int s = C >> 1; s > 0; s >>= 1) {
        if (c < s) { ss[t] += ss[t + s]; sd[t] += sd[t + s]; }
        __syncthreads();
    }
    if (c == 0) {
        int head = t / C;
        as_[n * H + head] = ss[t];
        ad_[n * H + head] = sd[t];
    }
}

// ---------------- fused CSR softmax + aggregate (fp16 gather) ----------------
// Wave split into 64/(HC/8) groups; group g handles edges s0+g, s0+g+GRP, ...
// Each lane owns 8 channels (16B fp16 load). Cross-group shfl_xor combine.

__device__ inline float edge_w(float a) {
    float e = a > 0.f ? a : NEG_SLOPE * a;
    return __expf(e);
}

template<int HC, int H, bool BF16OUT>
__global__ __launch_bounds__(64) void fused_agg(const int* __restrict__ row_start,
                                                const int* __restrict__ csr_src,
                                                const __half* __restrict__ h,
                                                const float* __restrict__ as_,
                                                const float* __restrict__ ad_,
                                                const float* __restrict__ bias,
                                                float* __restrict__ out,
                                                unsigned short* __restrict__ outh,
                                                unsigned short* __restrict__ outl) {
    constexpr int LPE = HC / 8;          // lanes per edge (32 or 16)
    constexpr int GRP = 64 / LPE;        // concurrent edges per wave (2 or 4)
    constexpr int C = HC / H;
    const int n = blockIdx.x;
    const int lane = threadIdx.x;
    const int g = lane / LPE;
    const int lq = lane % LPE;
    const int c0 = lq * 8;
    const int head = c0 / C;
    const int s0 = row_start[n], s1 = row_start[n + 1];
    const float adv = ad_[n * H + head];
    float acc[8] = {};
    float den = 0.f;
    int p = s0 + g;
    for (; p + 3 * GRP < s1; p += 4 * GRP) {
        int src0 = csr_src[p];
        int src1 = csr_src[p + GRP];
        int src2 = csr_src[p + 2 * GRP];
        int src3 = csr_src[p + 3 * GRP];
        float f0[8], f1[8], f2[8], f3[8];
        loadH8(f0, h + (size_t)src0 * HC + c0);
        loadH8(f1, h + (size_t)src1 * HC + c0);
        loadH8(f2, h + (size_t)src2 * HC + c0);
        loadH8(f3, h + (size_t)src3 * HC + c0);
        float w0 = edge_w(as_[src0 * H + head] + adv);
        float w1 = edge_w(as_[src1 * H + head] + adv);
        float w2 = edge_w(as_[src2 * H + head] + adv);
        float w3 = edge_w(as_[src3 * H + head] + adv);
        den += (w0 + w1) + (w2 + w3);
#pragma unroll
        for (int i = 0; i < 8; ++i)
            acc[i] += w0 * f0[i] + w1 * f1[i] + w2 * f2[i] + w3 * f3[i];
    }
    for (; p < s1; p += GRP) {
        int src = csr_src[p];
        float f[8];
        loadH8(f, h + (size_t)src * HC + c0);
        float w = edge_w(as_[src * H + head] + adv);
        den += w;
#pragma unroll
        for (int i = 0; i < 8; ++i) acc[i] += w * f[i];
    }
    // combine groups (xor masks >= LPE keep channel id, flip group id)
#pragma unroll
    for (int off = LPE; off < 64; off <<= 1) {
        den += __shfl_xor(den, off);
#pragma unroll
        for (int i = 0; i < 8; ++i) acc[i] += __shfl_xor(acc[i], off);
    }
    if (g == 0) {
        float dinv = 1.0f / (den + 1e-16f);
        float o[8];
#pragma unroll
        for (int i = 0; i < 8; ++i) {
            float v = acc[i] * dinv + bias[c0 + i];
            o[i] = v > 0.f ? v : 0.f;
        }
        if (BF16OUT) {
            s16x8 hb, lb;
#pragma unroll
            for (int i = 0; i < 8; ++i) {
                unsigned short hh = f2bf(o[i]);
                hb[i] = (short)hh;
                lb[i] = (short)f2bf(o[i] - bf2f(hh));
            }
            *(s16x8*)(outh + (size_t)n * HC + c0) = hb;
            *(s16x8*)(outl + (size_t)n * HC + c0) = lb;
        } else {
            float4 v0 = make_float4(o[0], o[1], o[2], o[3]);
            float4 v1 = make_float4(o[4], o[5], o[6], o[7]);
            *(float4*)(out + (size_t)n * HC + c0) = v0;
            *(float4*)(out + (size_t)n * HC + c0 + 4) = v1;
        }
    }
}

extern "C" void kernel_launch(void* const* d_in, const int* in_sizes, int n_in,
                              void* d_out, int out_size, void* d_ws, size_t ws_size,
                              hipStream_t stream) {
    const float* x      = (const float*)d_in[0];
    const int*   ei     = (const int*)d_in[1];
    const float* W1     = (const float*)d_in[2];
    const float* att_s1 = (const float*)d_in[3];
    const float* att_d1 = (const float*)d_in[4];
    const float* b1     = (const float*)d_in[5];
    const float* W2     = (const float*)d_in[6];
    const float* att_s2 = (const float*)d_in[7];
    const float* att_d2 = (const float*)d_in[8];
    const float* b2     = (const float*)d_in[9];
    float* out = (float*)d_out;

    const int N_ = in_sizes[0] / 128;   // 50000
    const int E_ = in_sizes[1] / 2;     // 800000
    const int Etot = E_ + N_;           // 850000

    // workspace layout
    __half* h1 = (__half*)d_ws;                              // N*256 fp16 (also h2)
    unsigned short* x2h = (unsigned short*)(h1 + (size_t)N_ * 256);  // N*256 bf16
    unsigned short* x2l = x2h + (size_t)N_ * 256;                    // N*256 bf16
    // x hi/lo overlay x2 (x split dead after gemm1, before agg1 writes x2):
    unsigned short* xh = x2h;                                // N*128 bf16
    unsigned short* xl = x2l;                                // N*128 bf16
    unsigned short* bp1h = x2l + (size_t)N_ * 256;           // 32768
    unsigned short* bp1l = bp1h + 32768;
    unsigned short* bp2h = bp1l + 32768;
    unsigned short* bp2l = bp2h + 32768;
    float* as1 = (float*)(bp2l + 32768);                     // N*4
    float* ad1 = as1 + (size_t)N_ * 4;                       // N*4
    float* as2 = ad1 + (size_t)N_ * 4;                       // N
    float* ad2 = as2 + N_;                                   // N
    int* cnt       = (int*)(ad2 + N_);                       // N
    int* row_start = cnt + N_;                               // N+1
    int* cursor    = row_start + (N_ + 1);                   // N
    int* csr_src   = cursor + N_;                            // Etot

    hipMemsetAsync(cnt, 0, (size_t)N_ * 4, stream);

    int eb = (Etot + 255) / 256;
    count_kernel<<<eb, 256, 0, stream>>>(ei, E_, N_, cnt);
    scan_kernel<<<1, 1024, 0, stream>>>(cnt, row_start, cursor, N_);
    fill_kernel<<<eb, 256, 0, stream>>>(ei, E_, N_, cursor, csr_src);

    // split x, pack weights
    split_kernel<<<((N_ * 128) + 255) / 256, 256, 0, stream>>>(x, xh, xl, N_ * 128);
    pack_w<<<(128 * 256 + 255) / 256, 256, 0, stream>>>(W1, bp1h, bp1l, 128, 256);
    pack_w<<<(256 * 128 + 255) / 256, 256, 0, stream>>>(W2, bp2h, bp2l, 256, 128);

    // ---- layer 1: 128 -> 4x64 ----
    mfma_gemm<128, 256><<<(N_ + 31) / 32, 256, 0, stream>>>(N_, xh, xl, bp1h, bp1l, h1);
    att_dots<<<N_, 256, 2 * 256 * sizeof(float), stream>>>(h1, att_s1, att_d1, as1, ad1, 4, 64);
    fused_agg<256, 4, true><<<N_, 64, 0, stream>>>(row_start, csr_src, h1, as1, ad1, b1,
                                                   nullptr, x2h, x2l);

    // ---- layer 2: 256 -> 1x128 ----
    __half* h2 = h1;  // reuse
    mfma_gemm<256, 128><<<(N_ + 63) / 64, 256, 0, stream>>>(N_, x2h, x2l, bp2h, bp2l, h2);
    att_dots<<<N_, 128, 2 * 128 * sizeof(float), stream>>>(h2, att_s2, att_d2, as2, ad2, 1, 128);
    fused_agg<128, 1, false><<<N_, 64, 0, stream>>>(row_start, csr_src, h2, as2, ad2, b2,
                                                    out, nullptr, nullptr);

    (void)n_in; (void)out_size; (void)ws_size;
}

// Round 5
// 424.762 us; speedup vs baseline: 2.3039x; 1.2323x over previous
//
#include <hip/hip_runtime.h>
#include <hip/hip_bf16.h>
#include <hip/hip_fp16.h>

// GAT 2-layer forward. N=50000, E=800000 (+N self loops).
// L1: 128 -> 4x64 concat 256, ReLU.  L2: 256 -> 128, ReLU.
// R1: fused CSR softmax+aggregate (one wave/node).
// R2: GEMMs via bf16 MFMA hi/lo split (Ah*Bh + Ah*Bl + Al*Bh ~ fp32).
// R3: h stored fp16; GEMM blocks cover full N; aggregation edge-groups.
// R4: parallel 3-pass scan (old single-block scan was 111 us -- top dispatch).

#define NEG_SLOPE 0.2f

typedef __attribute__((ext_vector_type(8))) short s16x8;   // 8 x 16-bit = 4 VGPRs
typedef __attribute__((ext_vector_type(4))) float f32x4;

__device__ inline unsigned short f2bf(float f) {            // RNE f32 -> bf16
    unsigned int u = __float_as_uint(f);
    u += 0x7fff + ((u >> 16) & 1);
    return (unsigned short)(u >> 16);
}
__device__ inline float bf2f(unsigned short h) {
    return __uint_as_float(((unsigned int)h) << 16);
}

// 16B load of 8 fp16 -> 8 fp32
__device__ inline void loadH8(float* v, const __half* p) {
    union { s16x8 raw; __half2 h2[4]; } u;
    u.raw = *(const s16x8*)p;
#pragma unroll
    for (int i = 0; i < 4; ++i) {
        float2 f = __half22float2(u.h2[i]);
        v[2 * i] = f.x;
        v[2 * i + 1] = f.y;
    }
}

// ---------------- CSR build ----------------

__global__ void count_kernel(const int* __restrict__ ei, int E, int N, int* __restrict__ cnt) {
    int e = blockIdx.x * blockDim.x + threadIdx.x;
    int Etot = E + N;
    if (e >= Etot) return;
    int d = (e < E) ? ei[E + e] : (e - E);
    atomicAdd(&cnt[d], 1);
}

// pass 1: per-block exclusive scan into row_start, block totals into bsum
__global__ void scan_blocks(const int* __restrict__ cnt, int* __restrict__ row_start,
                            int* __restrict__ bsum, int N) {
    __shared__ int sm[256];
    int t = threadIdx.x;
    int i = blockIdx.x * 256 + t;
    int c = (i < N) ? cnt[i] : 0;
    sm[t] = c;
    __syncthreads();
    for (int off = 1; off < 256; off <<= 1) {
        int v = (t >= off) ? sm[t - off] : 0;
        __syncthreads();
        sm[t] += v;
        __syncthreads();
    }
    if (i < N) row_start[i] = sm[t] - c;     // block-local exclusive
    if (t == 255) bsum[blockIdx.x] = sm[255];
}

// pass 2: one block scans block sums (nb <= 256) exclusive in-place; total -> row_start[N]
__global__ void scan_bsums(int* __restrict__ bsum, int* __restrict__ row_start, int nb, int N) {
    __shared__ int sm[256];
    int t = threadIdx.x;
    int v = (t < nb) ? bsum[t] : 0;
    sm[t] = v;
    __syncthreads();
    for (int off = 1; off < 256; off <<= 1) {
        int u = (t >= off) ? sm[t - off] : 0;
        __syncthreads();
        sm[t] += u;
        __syncthreads();
    }
    if (t < nb) bsum[t] = sm[t] - v;         // exclusive block offset
    if (t == 255) row_start[N] = sm[255];
}

// pass 3: add block offsets, mirror into cursor
__global__ void scan_add(int* __restrict__ row_start, const int* __restrict__ bsum,
                         int* __restrict__ cursor, int N) {
    int i = blockIdx.x * 256 + threadIdx.x;
    if (i >= N) return;
    int v = row_start[i] + bsum[blockIdx.x];
    row_start[i] = v;
    cursor[i] = v;
}

__global__ void fill_kernel(const int* __restrict__ ei, int E, int N, int* __restrict__ cursor,
                            int* __restrict__ csr_src) {
    int e = blockIdx.x * blockDim.x + threadIdx.x;
    int Etot = E + N;
    if (e >= Etot) return;
    int s, d;
    if (e < E) { s = ei[e]; d = ei[E + e]; } else { s = e - E; d = s; }
    int pos = atomicAdd(&cursor[d], 1);
    csr_src[pos] = s;
}

// ---------------- fp32 -> bf16 hi/lo split ----------------

__global__ void split_kernel(const float* __restrict__ in, unsigned short* __restrict__ hi,
                             unsigned short* __restrict__ lo, int n) {
    int i = blockIdx.x * blockDim.x + threadIdx.x;
    if (i >= n) return;
    float v = in[i];
    unsigned short h = f2bf(v);
    hi[i] = h;
    lo[i] = f2bf(v - bf2f(h));
}

// ---------------- pack W into MFMA B-fragment layout ----------------
// B-frag (16x16x32): lane l holds B[k0 + (l>>4)*8 + j][n0 + (l&15)], j=0..7.

__global__ void pack_w(const float* __restrict__ W, unsigned short* __restrict__ bph,
                       unsigned short* __restrict__ bpl, int K, int N) {
    int tid = blockIdx.x * blockDim.x + threadIdx.x;
    if (tid >= K * N) return;
    int k = tid / N, n = tid - k * N;
    int ks = k >> 5, k5 = k & 31, quad = k5 >> 3, j = k5 & 7;
    int ct = n >> 4;
    int lane = quad * 16 + (n & 15);
    size_t idx = ((size_t)(ct * (K >> 5) + ks) * 64 + lane) * 8 + j;
    float w = W[tid];
    unsigned short h = f2bf(w);
    bph[idx] = h;
    bpl[idx] = f2bf(w - bf2f(h));
}

// ---------------- split-precision bf16 MFMA GEMM, fp16 output ----------------

template<int K, int NN>
__global__ __launch_bounds__(256) void mfma_gemm(int M,
        const unsigned short* __restrict__ Ah, const unsigned short* __restrict__ Al,
        const unsigned short* __restrict__ Bph, const unsigned short* __restrict__ Bpl,
        __half* __restrict__ Hout) {
    constexpr int KS = K >> 5;
    constexpr int CW = NN / 64;            // waves across columns
    constexpr int RW = 4 / CW;             // row-wave groups per block
    const int lane = threadIdx.x & 63;
    const int w = threadIdx.x >> 6;
    const int wr = w / CW;
    const int wc = w % CW;
    const int quad = lane >> 4;
    const int r16 = lane & 15;
    const int mBase = blockIdx.x * (RW * 32) + wr * 32;
    const int nBase = wc * 64;

    f32x4 acc[2][4];
#pragma unroll
    for (int rt = 0; rt < 2; ++rt)
#pragma unroll
        for (int ct = 0; ct < 4; ++ct) acc[rt][ct] = (f32x4){0.f, 0.f, 0.f, 0.f};

#pragma unroll
    for (int ks = 0; ks < KS; ++ks) {
        s16x8 ahf[2], alf[2];
#pragma unroll
        for (int rt = 0; rt < 2; ++rt) {
            int row = mBase + rt * 16 + r16;
            if (row < M) {
                size_t off = (size_t)row * K + ks * 32 + quad * 8;
                ahf[rt] = *(const s16x8*)(Ah + off);
                alf[rt] = *(const s16x8*)(Al + off);
            } else {
                ahf[rt] = (s16x8){0,0,0,0,0,0,0,0};
                alf[rt] = (s16x8){0,0,0,0,0,0,0,0};
            }
        }
        s16x8 bhf[4], blf[4];
#pragma unroll
        for (int ct = 0; ct < 4; ++ct) {
            int ctg = (nBase >> 4) + ct;
            size_t off = ((size_t)(ctg * KS + ks) * 64 + lane) * 8;
            bhf[ct] = *(const s16x8*)(Bph + off);
            blf[ct] = *(const s16x8*)(Bpl + off);
        }
#pragma unroll
        for (int rt = 0; rt < 2; ++rt)
#pragma unroll
            for (int ct = 0; ct < 4; ++ct) {
                acc[rt][ct] = __builtin_amdgcn_mfma_f32_16x16x32_bf16(ahf[rt], bhf[ct], acc[rt][ct], 0, 0, 0);
                acc[rt][ct] = __builtin_amdgcn_mfma_f32_16x16x32_bf16(ahf[rt], blf[ct], acc[rt][ct], 0, 0, 0);
                acc[rt][ct] = __builtin_amdgcn_mfma_f32_16x16x32_bf16(alf[rt], bhf[ct], acc[rt][ct], 0, 0, 0);
            }
    }

    // C/D layout: lane l reg r -> row = (l>>4)*4 + r, col = l&15
#pragma unroll
    for (int rt = 0; rt < 2; ++rt)
#pragma unroll
        for (int ct = 0; ct < 4; ++ct) {
            int row0 = mBase + rt * 16 + quad * 4;
            int col = nBase + ct * 16 + r16;
#pragma unroll
            for (int r = 0; r < 4; ++r) {
                int row = row0 + r;
                if (row < M) Hout[(size_t)row * NN + col] = __float2half(acc[rt][ct][r]);
            }
        }
}

// ---------------- attention dots (fp16 h) ----------------

__global__ void att_dots(const __half* __restrict__ h, const float* __restrict__ att_s,
                         const float* __restrict__ att_d, float* __restrict__ as_,
                         float* __restrict__ ad_, int H, int C) {
    int n = blockIdx.x;
    int t = threadIdx.x;
    int HC = blockDim.x;
    int c = t & (C - 1);
    extern __shared__ float sm2[];
    float* ss = sm2;
    float* sd = sm2 + HC;
    float v = __half2float(h[(size_t)n * HC + t]);
    ss[t] = v * att_s[t];
    sd[t] = v * att_d[t];
    __syncthreads();
    for (int s = C >> 1; s > 0; s >>= 1) {
        if (c < s) { ss[t] += ss[t + s]; sd[t] += sd[t + s]; }
        __syncthreads();
    }
    if (c == 0) {
        int head = t / C;
        as_[n * H + head] = ss[t];
        ad_[n * H + head] = sd[t];
    }
}

// ---------------- fused CSR softmax + aggregate (fp16 gather) ----------------

__device__ inline float edge_w(float a) {
    float e = a > 0.f ? a : NEG_SLOPE * a;
    return __expf(e);
}

template<int HC, int H, bool BF16OUT>
__global__ __launch_bounds__(64) void fused_agg(const int* __restrict__ row_start,
                                                const int* __restrict__ csr_src,
                                                const __half* __restrict__ h,
                                                const float* __restrict__ as_,
                                                const float* __restrict__ ad_,
                                                const float* __restrict__ bias,
                                                float* __restrict__ out,
                                                unsigned short* __restrict__ outh,
                                                unsigned short* __restrict__ outl) {
    constexpr int LPE = HC / 8;          // lanes per edge (32 or 16)
    constexpr int GRP = 64 / LPE;        // concurrent edges per wave (2 or 4)
    constexpr int C = HC / H;
    const int n = blockIdx.x;
    const int lane = threadIdx.x;
    const int g = lane / LPE;
    const int lq = lane % LPE;
    const int c0 = lq * 8;
    const int head = c0 / C;
    const int s0 = row_start[n], s1 = row_start[n + 1];
    const float adv = ad_[n * H + head];
    float acc[8] = {};
    float den = 0.f;
    int p = s0 + g;
    for (; p + 3 * GRP < s1; p += 4 * GRP) {
        int src0 = csr_src[p];
        int src1 = csr_src[p + GRP];
        int src2 = csr_src[p + 2 * GRP];
        int src3 = csr_src[p + 3 * GRP];
        float f0[8], f1[8], f2[8], f3[8];
        loadH8(f0, h + (size_t)src0 * HC + c0);
        loadH8(f1, h + (size_t)src1 * HC + c0);
        loadH8(f2, h + (size_t)src2 * HC + c0);
        loadH8(f3, h + (size_t)src3 * HC + c0);
        float w0 = edge_w(as_[src0 * H + head] + adv);
        float w1 = edge_w(as_[src1 * H + head] + adv);
        float w2 = edge_w(as_[src2 * H + head] + adv);
        float w3 = edge_w(as_[src3 * H + head] + adv);
        den += (w0 + w1) + (w2 + w3);
#pragma unroll
        for (int i = 0; i < 8; ++i)
            acc[i] += w0 * f0[i] + w1 * f1[i] + w2 * f2[i] + w3 * f3[i];
    }
    for (; p < s1; p += GRP) {
        int src = csr_src[p];
        float f[8];
        loadH8(f, h + (size_t)src * HC + c0);
        float w = edge_w(as_[src * H + head] + adv);
        den += w;
#pragma unroll
        for (int i = 0; i < 8; ++i) acc[i] += w * f[i];
    }
#pragma unroll
    for (int off = LPE; off < 64; off <<= 1) {
        den += __shfl_xor(den, off);
#pragma unroll
        for (int i = 0; i < 8; ++i) acc[i] += __shfl_xor(acc[i], off);
    }
    if (g == 0) {
        float dinv = 1.0f / (den + 1e-16f);
        float o[8];
#pragma unroll
        for (int i = 0; i < 8; ++i) {
            float v = acc[i] * dinv + bias[c0 + i];
            o[i] = v > 0.f ? v : 0.f;
        }
        if (BF16OUT) {
            s16x8 hb, lb;
#pragma unroll
            for (int i = 0; i < 8; ++i) {
                unsigned short hh = f2bf(o[i]);
                hb[i] = (short)hh;
                lb[i] = (short)f2bf(o[i] - bf2f(hh));
            }
            *(s16x8*)(outh + (size_t)n * HC + c0) = hb;
            *(s16x8*)(outl + (size_t)n * HC + c0) = lb;
        } else {
            float4 v0 = make_float4(o[0], o[1], o[2], o[3]);
            float4 v1 = make_float4(o[4], o[5], o[6], o[7]);
            *(float4*)(out + (size_t)n * HC + c0) = v0;
            *(float4*)(out + (size_t)n * HC + c0 + 4) = v1;
        }
    }
}

extern "C" void kernel_launch(void* const* d_in, const int* in_sizes, int n_in,
                              void* d_out, int out_size, void* d_ws, size_t ws_size,
                              hipStream_t stream) {
    const float* x      = (const float*)d_in[0];
    const int*   ei     = (const int*)d_in[1];
    const float* W1     = (const float*)d_in[2];
    const float* att_s1 = (const float*)d_in[3];
    const float* att_d1 = (const float*)d_in[4];
    const float* b1     = (const float*)d_in[5];
    const float* W2     = (const float*)d_in[6];
    const float* att_s2 = (const float*)d_in[7];
    const float* att_d2 = (const float*)d_in[8];
    const float* b2     = (const float*)d_in[9];
    float* out = (float*)d_out;

    const int N_ = in_sizes[0] / 128;   // 50000
    const int E_ = in_sizes[1] / 2;     // 800000
    const int Etot = E_ + N_;           // 850000

    // workspace layout
    __half* h1 = (__half*)d_ws;                              // N*256 fp16 (also h2)
    unsigned short* x2h = (unsigned short*)(h1 + (size_t)N_ * 256);  // N*256 bf16
    unsigned short* x2l = x2h + (size_t)N_ * 256;                    // N*256 bf16
    // x hi/lo overlay x2 (x split dead after gemm1, before agg1 writes x2):
    unsigned short* xh = x2h;                                // N*128 bf16
    unsigned short* xl = x2l;                                // N*128 bf16
    unsigned short* bp1h = x2l + (size_t)N_ * 256;           // 32768
    unsigned short* bp1l = bp1h + 32768;
    unsigned short* bp2h = bp1l + 32768;
    unsigned short* bp2l = bp2h + 32768;
    float* as1 = (float*)(bp2l + 32768);                     // N*4
    float* ad1 = as1 + (size_t)N_ * 4;                       // N*4
    float* as2 = ad1 + (size_t)N_ * 4;                       // N
    float* ad2 = as2 + N_;                                   // N
    int* cnt       = (int*)(ad2 + N_);                       // N
    int* row_start = cnt + N_;                               // N+1
    int* cursor    = row_start + (N_ + 1);                   // N
    int* bsum      = cursor + N_;                            // 256
    int* csr_src   = bsum + 256;                             // Etot

    hipMemsetAsync(cnt, 0, (size_t)N_ * 4, stream);

    int eb = (Etot + 255) / 256;
    int nb = (N_ + 255) / 256;          // 196
    count_kernel<<<eb, 256, 0, stream>>>(ei, E_, N_, cnt);
    scan_blocks<<<nb, 256, 0, stream>>>(cnt, row_start, bsum, N_);
    scan_bsums<<<1, 256, 0, stream>>>(bsum, row_start, nb, N_);
    scan_add<<<nb, 256, 0, stream>>>(row_start, bsum, cursor, N_);
    fill_kernel<<<eb, 256, 0, stream>>>(ei, E_, N_, cursor, csr_src);

    // split x, pack weights
    split_kernel<<<((N_ * 128) + 255) / 256, 256, 0, stream>>>(x, xh, xl, N_ * 128);
    pack_w<<<(128 * 256 + 255) / 256, 256, 0, stream>>>(W1, bp1h, bp1l, 128, 256);
    pack_w<<<(256 * 128 + 255) / 256, 256, 0, stream>>>(W2, bp2h, bp2l, 256, 128);

    // ---- layer 1: 128 -> 4x64 ----
    mfma_gemm<128, 256><<<(N_ + 31) / 32, 256, 0, stream>>>(N_, xh, xl, bp1h, bp1l, h1);
    att_dots<<<N_, 256, 2 * 256 * sizeof(float), stream>>>(h1, att_s1, att_d1, as1, ad1, 4, 64);
    fused_agg<256, 4, true><<<N_, 64, 0, stream>>>(row_start, csr_src, h1, as1, ad1, b1,
                                                   nullptr, x2h, x2l);

    // ---- layer 2: 256 -> 1x128 ----
    __half* h2 = h1;  // reuse
    mfma_gemm<256, 128><<<(N_ + 63) / 64, 256, 0, stream>>>(N_, x2h, x2l, bp2h, bp2l, h2);
    att_dots<<<N_, 128, 2 * 128 * sizeof(float), stream>>>(h2, att_s2, att_d2, as2, ad2, 1, 128);
    fused_agg<128, 1, false><<<N_, 64, 0, stream>>>(row_start, csr_src, h2, as2, ad2, b2,
                                                    out, nullptr, nullptr);

    (void)n_in; (void)out_size; (void)ws_size;
}

// Round 6
// 364.070 us; speedup vs baseline: 2.6880x; 1.1667x over previous
//
#include <hip/hip_runtime.h>
#include <hip/hip_bf16.h>
#include <hip/hip_fp16.h>

// GAT 2-layer forward. N=50000, E=800000 (+N self loops).
// L1: 128 -> 4x64 concat 256, ReLU.  L2: 256 -> 128, ReLU.
// R1: fused CSR softmax+aggregate (one wave/node).
// R2: GEMMs via bf16 MFMA hi/lo split (Ah*Bh + Ah*Bl + Al*Bh ~ fp32).
// R3: h stored fp16; GEMM blocks cover full N; aggregation edge-groups.
// R4: parallel 3-pass scan.
// R5: att_dots fused into GEMM epilogue (shfl-reduce C-fragment; GEMM1 wave
//     covers exactly one head -> direct store, GEMM2 half-head -> atomicAdd);
//     agg edge unroll cascade 8/4/1 (HC=256) for more loads in flight.

#define NEG_SLOPE 0.2f

typedef __attribute__((ext_vector_type(8))) short s16x8;   // 8 x 16-bit = 4 VGPRs
typedef __attribute__((ext_vector_type(4))) float f32x4;

__device__ inline unsigned short f2bf(float f) {            // RNE f32 -> bf16
    unsigned int u = __float_as_uint(f);
    u += 0x7fff + ((u >> 16) & 1);
    return (unsigned short)(u >> 16);
}
__device__ inline float bf2f(unsigned short h) {
    return __uint_as_float(((unsigned int)h) << 16);
}

// 16B load of 8 fp16 -> 8 fp32
__device__ inline void loadH8(float* v, const __half* p) {
    union { s16x8 raw; __half2 h2[4]; } u;
    u.raw = *(const s16x8*)p;
#pragma unroll
    for (int i = 0; i < 4; ++i) {
        float2 f = __half22float2(u.h2[i]);
        v[2 * i] = f.x;
        v[2 * i + 1] = f.y;
    }
}

// ---------------- CSR build ----------------

__global__ void count_kernel(const int* __restrict__ ei, int E, int N, int* __restrict__ cnt) {
    int e = blockIdx.x * blockDim.x + threadIdx.x;
    int Etot = E + N;
    if (e >= Etot) return;
    int d = (e < E) ? ei[E + e] : (e - E);
    atomicAdd(&cnt[d], 1);
}

__global__ void scan_blocks(const int* __restrict__ cnt, int* __restrict__ row_start,
                            int* __restrict__ bsum, int N) {
    __shared__ int sm[256];
    int t = threadIdx.x;
    int i = blockIdx.x * 256 + t;
    int c = (i < N) ? cnt[i] : 0;
    sm[t] = c;
    __syncthreads();
    for (int off = 1; off < 256; off <<= 1) {
        int v = (t >= off) ? sm[t - off] : 0;
        __syncthreads();
        sm[t] += v;
        __syncthreads();
    }
    if (i < N) row_start[i] = sm[t] - c;
    if (t == 255) bsum[blockIdx.x] = sm[255];
}

__global__ void scan_bsums(int* __restrict__ bsum, int* __restrict__ row_start, int nb, int N) {
    __shared__ int sm[256];
    int t = threadIdx.x;
    int v = (t < nb) ? bsum[t] : 0;
    sm[t] = v;
    __syncthreads();
    for (int off = 1; off < 256; off <<= 1) {
        int u = (t >= off) ? sm[t - off] : 0;
        __syncthreads();
        sm[t] += u;
        __syncthreads();
    }
    if (t < nb) bsum[t] = sm[t] - v;
    if (t == 255) row_start[N] = sm[255];
}

__global__ void scan_add(int* __restrict__ row_start, const int* __restrict__ bsum,
                         int* __restrict__ cursor, int N) {
    int i = blockIdx.x * 256 + threadIdx.x;
    if (i >= N) return;
    int v = row_start[i] + bsum[blockIdx.x];
    row_start[i] = v;
    cursor[i] = v;
}

__global__ void fill_kernel(const int* __restrict__ ei, int E, int N, int* __restrict__ cursor,
                            int* __restrict__ csr_src) {
    int e = blockIdx.x * blockDim.x + threadIdx.x;
    int Etot = E + N;
    if (e >= Etot) return;
    int s, d;
    if (e < E) { s = ei[e]; d = ei[E + e]; } else { s = e - E; d = s; }
    int pos = atomicAdd(&cursor[d], 1);
    csr_src[pos] = s;
}

// ---------------- fp32 -> bf16 hi/lo split ----------------

__global__ void split_kernel(const float* __restrict__ in, unsigned short* __restrict__ hi,
                             unsigned short* __restrict__ lo, int n) {
    int i = blockIdx.x * blockDim.x + threadIdx.x;
    if (i >= n) return;
    float v = in[i];
    unsigned short h = f2bf(v);
    hi[i] = h;
    lo[i] = f2bf(v - bf2f(h));
}

// ---------------- pack W into MFMA B-fragment layout ----------------
// B-frag (16x16x32): lane l holds B[k0 + (l>>4)*8 + j][n0 + (l&15)], j=0..7.

__global__ void pack_w(const float* __restrict__ W, unsigned short* __restrict__ bph,
                       unsigned short* __restrict__ bpl, int K, int N) {
    int tid = blockIdx.x * blockDim.x + threadIdx.x;
    if (tid >= K * N) return;
    int k = tid / N, n = tid - k * N;
    int ks = k >> 5, k5 = k & 31, quad = k5 >> 3, j = k5 & 7;
    int ct = n >> 4;
    int lane = quad * 16 + (n & 15);
    size_t idx = ((size_t)(ct * (K >> 5) + ks) * 64 + lane) * 8 + j;
    float w = W[tid];
    unsigned short h = f2bf(w);
    bph[idx] = h;
    bpl[idx] = f2bf(w - bf2f(h));
}

// ---------------- split-precision bf16 MFMA GEMM + fused attention dots ----
// One block covers all NN columns. Epilogue computes a_s/a_d from fp32 acc:
// wave's 64 cols span head(s); ATOMIC=false when cols == full head (GEMM1),
// ATOMIC=true when cols are a partial head (GEMM2, atomicAdd combine).

template<int K, int NN, int H, bool ATOMIC>
__global__ __launch_bounds__(256) void mfma_gemm(int M,
        const unsigned short* __restrict__ Ah, const unsigned short* __restrict__ Al,
        const unsigned short* __restrict__ Bph, const unsigned short* __restrict__ Bpl,
        const float* __restrict__ att_s, const float* __restrict__ att_d,
        float* __restrict__ as_, float* __restrict__ ad_,
        __half* __restrict__ Hout) {
    constexpr int KS = K >> 5;
    constexpr int CW = NN / 64;            // waves across columns
    constexpr int RW = 4 / CW;             // row-wave groups per block
    constexpr int C = NN / H;              // channels per head
    const int lane = threadIdx.x & 63;
    const int w = threadIdx.x >> 6;
    const int wr = w / CW;
    const int wc = w % CW;
    const int quad = lane >> 4;
    const int r16 = lane & 15;
    const int mBase = blockIdx.x * (RW * 32) + wr * 32;
    const int nBase = wc * 64;
    const int head = nBase / C;

    f32x4 acc[2][4];
#pragma unroll
    for (int rt = 0; rt < 2; ++rt)
#pragma unroll
        for (int ct = 0; ct < 4; ++ct) acc[rt][ct] = (f32x4){0.f, 0.f, 0.f, 0.f};

#pragma unroll
    for (int ks = 0; ks < KS; ++ks) {
        s16x8 ahf[2], alf[2];
#pragma unroll
        for (int rt = 0; rt < 2; ++rt) {
            int row = mBase + rt * 16 + r16;
            if (row < M) {
                size_t off = (size_t)row * K + ks * 32 + quad * 8;
                ahf[rt] = *(const s16x8*)(Ah + off);
                alf[rt] = *(const s16x8*)(Al + off);
            } else {
                ahf[rt] = (s16x8){0,0,0,0,0,0,0,0};
                alf[rt] = (s16x8){0,0,0,0,0,0,0,0};
            }
        }
        s16x8 bhf[4], blf[4];
#pragma unroll
        for (int ct = 0; ct < 4; ++ct) {
            int ctg = (nBase >> 4) + ct;
            size_t off = ((size_t)(ctg * KS + ks) * 64 + lane) * 8;
            bhf[ct] = *(const s16x8*)(Bph + off);
            blf[ct] = *(const s16x8*)(Bpl + off);
        }
#pragma unroll
        for (int rt = 0; rt < 2; ++rt)
#pragma unroll
            for (int ct = 0; ct < 4; ++ct) {
                acc[rt][ct] = __builtin_amdgcn_mfma_f32_16x16x32_bf16(ahf[rt], bhf[ct], acc[rt][ct], 0, 0, 0);
                acc[rt][ct] = __builtin_amdgcn_mfma_f32_16x16x32_bf16(ahf[rt], blf[ct], acc[rt][ct], 0, 0, 0);
                acc[rt][ct] = __builtin_amdgcn_mfma_f32_16x16x32_bf16(alf[rt], bhf[ct], acc[rt][ct], 0, 0, 0);
            }
    }

    // ---- store h (fp16); C/D layout: lane l reg r -> row=(l>>4)*4+r, col=l&15
#pragma unroll
    for (int rt = 0; rt < 2; ++rt)
#pragma unroll
        for (int ct = 0; ct < 4; ++ct) {
            int row0 = mBase + rt * 16 + quad * 4;
            int col = nBase + ct * 16 + r16;
#pragma unroll
            for (int r = 0; r < 4; ++r) {
                int row = row0 + r;
                if (row < M) Hout[(size_t)row * NN + col] = __float2half(acc[rt][ct][r]);
            }
        }

    // ---- fused attention dots
    float attS[4], attD[4];
#pragma unroll
    for (int ct = 0; ct < 4; ++ct) {
        int cc = (nBase % C) + ct * 16 + r16;   // channel within head
        attS[ct] = att_s[head * C + cc];
        attD[ct] = att_d[head * C + cc];
    }
#pragma unroll
    for (int rt = 0; rt < 2; ++rt)
#pragma unroll
        for (int r = 0; r < 4; ++r) {
            float ps = 0.f, pd = 0.f;
#pragma unroll
            for (int ct = 0; ct < 4; ++ct) {
                ps += acc[rt][ct][r] * attS[ct];
                pd += acc[rt][ct][r] * attD[ct];
            }
#pragma unroll
            for (int off = 1; off < 16; off <<= 1) {
                ps += __shfl_xor(ps, off);
                pd += __shfl_xor(pd, off);
            }
            int row = mBase + rt * 16 + quad * 4 + r;
            if (r16 == 0 && row < M) {
                if (ATOMIC) {
                    atomicAdd(&as_[row * H + head], ps);
                    atomicAdd(&ad_[row * H + head], pd);
                } else {
                    as_[row * H + head] = ps;
                    ad_[row * H + head] = pd;
                }
            }
        }
}

// ---------------- fused CSR softmax + aggregate (fp16 gather) ----------------

__device__ inline float edge_w(float a) {
    float e = a > 0.f ? a : NEG_SLOPE * a;
    return __expf(e);
}

template<int U, int HC, int H, int GRP>
__device__ inline void agg_step(int p, const int* __restrict__ csr_src,
                                const __half* __restrict__ h,
                                const float* __restrict__ as_, float adv,
                                int c0, int head, float* acc, float& den) {
    int srcv[U];
#pragma unroll
    for (int u = 0; u < U; ++u) srcv[u] = csr_src[p + u * GRP];
    float f[U][8];
#pragma unroll
    for (int u = 0; u < U; ++u) loadH8(f[u], h + (size_t)srcv[u] * HC + c0);
    float wv[U];
#pragma unroll
    for (int u = 0; u < U; ++u) wv[u] = edge_w(as_[srcv[u] * H + head] + adv);
#pragma unroll
    for (int u = 0; u < U; ++u) den += wv[u];
#pragma unroll
    for (int u = 0; u < U; ++u)
#pragma unroll
        for (int i = 0; i < 8; ++i) acc[i] += wv[u] * f[u][i];
}

template<int HC, int H, bool BF16OUT>
__global__ __launch_bounds__(64) void fused_agg(const int* __restrict__ row_start,
                                                const int* __restrict__ csr_src,
                                                const __half* __restrict__ h,
                                                const float* __restrict__ as_,
                                                const float* __restrict__ ad_,
                                                const float* __restrict__ bias,
                                                float* __restrict__ out,
                                                unsigned short* __restrict__ outh,
                                                unsigned short* __restrict__ outl) {
    constexpr int LPE = HC / 8;          // lanes per edge (32 or 16)
    constexpr int GRP = 64 / LPE;        // concurrent edges per wave (2 or 4)
    constexpr int C = HC / H;
    const int n = blockIdx.x;
    const int lane = threadIdx.x;
    const int g = lane / LPE;
    const int lq = lane % LPE;
    const int c0 = lq * 8;
    const int head = c0 / C;
    const int s0 = row_start[n], s1 = row_start[n + 1];
    const float adv = ad_[n * H + head];
    float acc[8] = {};
    float den = 0.f;
    int p = s0 + g;
    if (GRP == 2) {   // HC=256: deeper pipeline
        for (; p + 7 * GRP < s1; p += 8 * GRP)
            agg_step<8, HC, H, GRP>(p, csr_src, h, as_, adv, c0, head, acc, den);
    }
    for (; p + 3 * GRP < s1; p += 4 * GRP)
        agg_step<4, HC, H, GRP>(p, csr_src, h, as_, adv, c0, head, acc, den);
    for (; p < s1; p += GRP)
        agg_step<1, HC, H, GRP>(p, csr_src, h, as_, adv, c0, head, acc, den);
#pragma unroll
    for (int off = LPE; off < 64; off <<= 1) {
        den += __shfl_xor(den, off);
#pragma unroll
        for (int i = 0; i < 8; ++i) acc[i] += __shfl_xor(acc[i], off);
    }
    if (g == 0) {
        float dinv = 1.0f / (den + 1e-16f);
        float o[8];
#pragma unroll
        for (int i = 0; i < 8; ++i) {
            float v = acc[i] * dinv + bias[c0 + i];
            o[i] = v > 0.f ? v : 0.f;
        }
        if (BF16OUT) {
            s16x8 hb, lb;
#pragma unroll
            for (int i = 0; i < 8; ++i) {
                unsigned short hh = f2bf(o[i]);
                hb[i] = (short)hh;
                lb[i] = (short)f2bf(o[i] - bf2f(hh));
            }
            *(s16x8*)(outh + (size_t)n * HC + c0) = hb;
            *(s16x8*)(outl + (size_t)n * HC + c0) = lb;
        } else {
            float4 v0 = make_float4(o[0], o[1], o[2], o[3]);
            float4 v1 = make_float4(o[4], o[5], o[6], o[7]);
            *(float4*)(out + (size_t)n * HC + c0) = v0;
            *(float4*)(out + (size_t)n * HC + c0 + 4) = v1;
        }
    }
}

extern "C" void kernel_launch(void* const* d_in, const int* in_sizes, int n_in,
                              void* d_out, int out_size, void* d_ws, size_t ws_size,
                              hipStream_t stream) {
    const float* x      = (const float*)d_in[0];
    const int*   ei     = (const int*)d_in[1];
    const float* W1     = (const float*)d_in[2];
    const float* att_s1 = (const float*)d_in[3];
    const float* att_d1 = (const float*)d_in[4];
    const float* b1     = (const float*)d_in[5];
    const float* W2     = (const float*)d_in[6];
    const float* att_s2 = (const float*)d_in[7];
    const float* att_d2 = (const float*)d_in[8];
    const float* b2     = (const float*)d_in[9];
    float* out = (float*)d_out;

    const int N_ = in_sizes[0] / 128;   // 50000
    const int E_ = in_sizes[1] / 2;     // 800000
    const int Etot = E_ + N_;           // 850000

    // workspace layout
    __half* h1 = (__half*)d_ws;                              // N*256 fp16 (also h2)
    unsigned short* x2h = (unsigned short*)(h1 + (size_t)N_ * 256);  // N*256 bf16
    unsigned short* x2l = x2h + (size_t)N_ * 256;                    // N*256 bf16
    unsigned short* xh = x2h;                                // N*128 bf16 (overlay)
    unsigned short* xl = x2l;                                // N*128 bf16 (overlay)
    unsigned short* bp1h = x2l + (size_t)N_ * 256;           // 32768
    unsigned short* bp1l = bp1h + 32768;
    unsigned short* bp2h = bp1l + 32768;
    unsigned short* bp2l = bp2h + 32768;
    float* as1 = (float*)(bp2l + 32768);                     // N*4
    float* ad1 = as1 + (size_t)N_ * 4;                       // N*4
    float* as2 = ad1 + (size_t)N_ * 4;                       // N
    float* ad2 = as2 + N_;                                   // N
    int* cnt       = (int*)(ad2 + N_);                       // N
    int* row_start = cnt + N_;                               // N+1
    int* cursor    = row_start + (N_ + 1);                   // N
    int* bsum      = cursor + N_;                            // 256
    int* csr_src   = bsum + 256;                             // Etot

    hipMemsetAsync(cnt, 0, (size_t)N_ * 4, stream);
    hipMemsetAsync(as2, 0, (size_t)N_ * 2 * 4, stream);      // as2+ad2 (atomic targets)

    int eb = (Etot + 255) / 256;
    int nb = (N_ + 255) / 256;          // 196
    count_kernel<<<eb, 256, 0, stream>>>(ei, E_, N_, cnt);
    scan_blocks<<<nb, 256, 0, stream>>>(cnt, row_start, bsum, N_);
    scan_bsums<<<1, 256, 0, stream>>>(bsum, row_start, nb, N_);
    scan_add<<<nb, 256, 0, stream>>>(row_start, bsum, cursor, N_);
    fill_kernel<<<eb, 256, 0, stream>>>(ei, E_, N_, cursor, csr_src);

    split_kernel<<<((N_ * 128) + 255) / 256, 256, 0, stream>>>(x, xh, xl, N_ * 128);
    pack_w<<<(128 * 256 + 255) / 256, 256, 0, stream>>>(W1, bp1h, bp1l, 128, 256);
    pack_w<<<(256 * 128 + 255) / 256, 256, 0, stream>>>(W2, bp2h, bp2l, 256, 128);

    // ---- layer 1: 128 -> 4x64 ----
    mfma_gemm<128, 256, 4, false><<<(N_ + 31) / 32, 256, 0, stream>>>(
        N_, xh, xl, bp1h, bp1l, att_s1, att_d1, as1, ad1, h1);
    fused_agg<256, 4, true><<<N_, 64, 0, stream>>>(row_start, csr_src, h1, as1, ad1, b1,
                                                   nullptr, x2h, x2l);

    // ---- layer 2: 256 -> 1x128 ----
    __half* h2 = h1;  // reuse
    mfma_gemm<256, 128, 1, true><<<(N_ + 63) / 64, 256, 0, stream>>>(
        N_, x2h, x2l, bp2h, bp2l, att_s2, att_d2, as2, ad2, h2);
    fused_agg<128, 1, false><<<N_, 64, 0, stream>>>(row_start, csr_src, h2, as2, ad2, b2,
                                                    out, nullptr, nullptr);

    (void)n_in; (void)out_size; (void)ws_size;
}

// Round 7
// 357.041 us; speedup vs baseline: 2.7409x; 1.0197x over previous
//
#include <hip/hip_runtime.h>
#include <hip/hip_bf16.h>
#include <hip/hip_fp16.h>

// GAT 2-layer forward. N=50000, E=800000 (+N self loops).
// L1: 128 -> 4x64 concat 256, ReLU.  L2: 256 -> 128, ReLU.
// R1: fused CSR softmax+aggregate.
// R2: GEMMs via bf16 MFMA hi/lo split (Ah*Bh + Ah*Bl + Al*Bh ~ fp32).
// R3: h stored fp16; GEMM blocks cover full N; aggregation edge-groups.
// R4: parallel 3-pass scan.
// R5: att_dots fused into GEMM epilogue.
// R6: agg packs 4 nodes per 256-thread block (64-thd WGs capped occupancy at
//     ~49% -- WG-slot limited); 8-deep unroll reverted (neutral, cost VGPRs).

#define NEG_SLOPE 0.2f

typedef __attribute__((ext_vector_type(8))) short s16x8;   // 8 x 16-bit = 4 VGPRs
typedef __attribute__((ext_vector_type(4))) float f32x4;

__device__ inline unsigned short f2bf(float f) {            // RNE f32 -> bf16
    unsigned int u = __float_as_uint(f);
    u += 0x7fff + ((u >> 16) & 1);
    return (unsigned short)(u >> 16);
}
__device__ inline float bf2f(unsigned short h) {
    return __uint_as_float(((unsigned int)h) << 16);
}

// 16B load of 8 fp16 -> 8 fp32
__device__ inline void loadH8(float* v, const __half* p) {
    union { s16x8 raw; __half2 h2[4]; } u;
    u.raw = *(const s16x8*)p;
#pragma unroll
    for (int i = 0; i < 4; ++i) {
        float2 f = __half22float2(u.h2[i]);
        v[2 * i] = f.x;
        v[2 * i + 1] = f.y;
    }
}

// ---------------- CSR build ----------------

__global__ void count_kernel(const int* __restrict__ ei, int E, int N, int* __restrict__ cnt) {
    int e = blockIdx.x * blockDim.x + threadIdx.x;
    int Etot = E + N;
    if (e >= Etot) return;
    int d = (e < E) ? ei[E + e] : (e - E);
    atomicAdd(&cnt[d], 1);
}

__global__ void scan_blocks(const int* __restrict__ cnt, int* __restrict__ row_start,
                            int* __restrict__ bsum, int N) {
    __shared__ int sm[256];
    int t = threadIdx.x;
    int i = blockIdx.x * 256 + t;
    int c = (i < N) ? cnt[i] : 0;
    sm[t] = c;
    __syncthreads();
    for (int off = 1; off < 256; off <<= 1) {
        int v = (t >= off) ? sm[t - off] : 0;
        __syncthreads();
        sm[t] += v;
        __syncthreads();
    }
    if (i < N) row_start[i] = sm[t] - c;
    if (t == 255) bsum[blockIdx.x] = sm[255];
}

__global__ void scan_bsums(int* __restrict__ bsum, int* __restrict__ row_start, int nb, int N) {
    __shared__ int sm[256];
    int t = threadIdx.x;
    int v = (t < nb) ? bsum[t] : 0;
    sm[t] = v;
    __syncthreads();
    for (int off = 1; off < 256; off <<= 1) {
        int u = (t >= off) ? sm[t - off] : 0;
        __syncthreads();
        sm[t] += u;
        __syncthreads();
    }
    if (t < nb) bsum[t] = sm[t] - v;
    if (t == 255) row_start[N] = sm[255];
}

__global__ void scan_add(int* __restrict__ row_start, const int* __restrict__ bsum,
                         int* __restrict__ cursor, int N) {
    int i = blockIdx.x * 256 + threadIdx.x;
    if (i >= N) return;
    int v = row_start[i] + bsum[blockIdx.x];
    row_start[i] = v;
    cursor[i] = v;
}

__global__ void fill_kernel(const int* __restrict__ ei, int E, int N, int* __restrict__ cursor,
                            int* __restrict__ csr_src) {
    int e = blockIdx.x * blockDim.x + threadIdx.x;
    int Etot = E + N;
    if (e >= Etot) return;
    int s, d;
    if (e < E) { s = ei[e]; d = ei[E + e]; } else { s = e - E; d = s; }
    int pos = atomicAdd(&cursor[d], 1);
    csr_src[pos] = s;
}

// ---------------- fp32 -> bf16 hi/lo split ----------------

__global__ void split_kernel(const float* __restrict__ in, unsigned short* __restrict__ hi,
                             unsigned short* __restrict__ lo, int n) {
    int i = blockIdx.x * blockDim.x + threadIdx.x;
    if (i >= n) return;
    float v = in[i];
    unsigned short h = f2bf(v);
    hi[i] = h;
    lo[i] = f2bf(v - bf2f(h));
}

// ---------------- pack W into MFMA B-fragment layout ----------------
// B-frag (16x16x32): lane l holds B[k0 + (l>>4)*8 + j][n0 + (l&15)], j=0..7.

__global__ void pack_w(const float* __restrict__ W, unsigned short* __restrict__ bph,
                       unsigned short* __restrict__ bpl, int K, int N) {
    int tid = blockIdx.x * blockDim.x + threadIdx.x;
    if (tid >= K * N) return;
    int k = tid / N, n = tid - k * N;
    int ks = k >> 5, k5 = k & 31, quad = k5 >> 3, j = k5 & 7;
    int ct = n >> 4;
    int lane = quad * 16 + (n & 15);
    size_t idx = ((size_t)(ct * (K >> 5) + ks) * 64 + lane) * 8 + j;
    float w = W[tid];
    unsigned short h = f2bf(w);
    bph[idx] = h;
    bpl[idx] = f2bf(w - bf2f(h));
}

// ---------------- split-precision bf16 MFMA GEMM + fused attention dots ----

template<int K, int NN, int H, bool ATOMIC>
__global__ __launch_bounds__(256) void mfma_gemm(int M,
        const unsigned short* __restrict__ Ah, const unsigned short* __restrict__ Al,
        const unsigned short* __restrict__ Bph, const unsigned short* __restrict__ Bpl,
        const float* __restrict__ att_s, const float* __restrict__ att_d,
        float* __restrict__ as_, float* __restrict__ ad_,
        __half* __restrict__ Hout) {
    constexpr int KS = K >> 5;
    constexpr int CW = NN / 64;            // waves across columns
    constexpr int RW = 4 / CW;             // row-wave groups per block
    constexpr int C = NN / H;              // channels per head
    const int lane = threadIdx.x & 63;
    const int w = threadIdx.x >> 6;
    const int wr = w / CW;
    const int wc = w % CW;
    const int quad = lane >> 4;
    const int r16 = lane & 15;
    const int mBase = blockIdx.x * (RW * 32) + wr * 32;
    const int nBase = wc * 64;
    const int head = nBase / C;

    f32x4 acc[2][4];
#pragma unroll
    for (int rt = 0; rt < 2; ++rt)
#pragma unroll
        for (int ct = 0; ct < 4; ++ct) acc[rt][ct] = (f32x4){0.f, 0.f, 0.f, 0.f};

#pragma unroll
    for (int ks = 0; ks < KS; ++ks) {
        s16x8 ahf[2], alf[2];
#pragma unroll
        for (int rt = 0; rt < 2; ++rt) {
            int row = mBase + rt * 16 + r16;
            if (row < M) {
                size_t off = (size_t)row * K + ks * 32 + quad * 8;
                ahf[rt] = *(const s16x8*)(Ah + off);
                alf[rt] = *(const s16x8*)(Al + off);
            } else {
                ahf[rt] = (s16x8){0,0,0,0,0,0,0,0};
                alf[rt] = (s16x8){0,0,0,0,0,0,0,0};
            }
        }
        s16x8 bhf[4], blf[4];
#pragma unroll
        for (int ct = 0; ct < 4; ++ct) {
            int ctg = (nBase >> 4) + ct;
            size_t off = ((size_t)(ctg * KS + ks) * 64 + lane) * 8;
            bhf[ct] = *(const s16x8*)(Bph + off);
            blf[ct] = *(const s16x8*)(Bpl + off);
        }
#pragma unroll
        for (int rt = 0; rt < 2; ++rt)
#pragma unroll
            for (int ct = 0; ct < 4; ++ct) {
                acc[rt][ct] = __builtin_amdgcn_mfma_f32_16x16x32_bf16(ahf[rt], bhf[ct], acc[rt][ct], 0, 0, 0);
                acc[rt][ct] = __builtin_amdgcn_mfma_f32_16x16x32_bf16(ahf[rt], blf[ct], acc[rt][ct], 0, 0, 0);
                acc[rt][ct] = __builtin_amdgcn_mfma_f32_16x16x32_bf16(alf[rt], bhf[ct], acc[rt][ct], 0, 0, 0);
            }
    }

    // ---- store h (fp16); C/D layout: lane l reg r -> row=(l>>4)*4+r, col=l&15
#pragma unroll
    for (int rt = 0; rt < 2; ++rt)
#pragma unroll
        for (int ct = 0; ct < 4; ++ct) {
            int row0 = mBase + rt * 16 + quad * 4;
            int col = nBase + ct * 16 + r16;
#pragma unroll
            for (int r = 0; r < 4; ++r) {
                int row = row0 + r;
                if (row < M) Hout[(size_t)row * NN + col] = __float2half(acc[rt][ct][r]);
            }
        }

    // ---- fused attention dots
    float attS[4], attD[4];
#pragma unroll
    for (int ct = 0; ct < 4; ++ct) {
        int cc = (nBase % C) + ct * 16 + r16;   // channel within head
        attS[ct] = att_s[head * C + cc];
        attD[ct] = att_d[head * C + cc];
    }
#pragma unroll
    for (int rt = 0; rt < 2; ++rt)
#pragma unroll
        for (int r = 0; r < 4; ++r) {
            float ps = 0.f, pd = 0.f;
#pragma unroll
            for (int ct = 0; ct < 4; ++ct) {
                ps += acc[rt][ct][r] * attS[ct];
                pd += acc[rt][ct][r] * attD[ct];
            }
#pragma unroll
            for (int off = 1; off < 16; off <<= 1) {
                ps += __shfl_xor(ps, off);
                pd += __shfl_xor(pd, off);
            }
            int row = mBase + rt * 16 + quad * 4 + r;
            if (r16 == 0 && row < M) {
                if (ATOMIC) {
                    atomicAdd(&as_[row * H + head], ps);
                    atomicAdd(&ad_[row * H + head], pd);
                } else {
                    as_[row * H + head] = ps;
                    ad_[row * H + head] = pd;
                }
            }
        }
}

// ---------------- fused CSR softmax + aggregate (fp16 gather) ----------------
// 256-thread block = 4 independent waves, wave w handles node blk*4+w.
// Within a wave: LPE lanes per edge, GRP edges concurrent, 4-edge unroll.

__device__ inline float edge_w(float a) {
    float e = a > 0.f ? a : NEG_SLOPE * a;
    return __expf(e);
}

template<int U, int HC, int H, int GRP>
__device__ inline void agg_step(int p, const int* __restrict__ csr_src,
                                const __half* __restrict__ h,
                                const float* __restrict__ as_, float adv,
                                int c0, int head, float* acc, float& den) {
    int srcv[U];
#pragma unroll
    for (int u = 0; u < U; ++u) srcv[u] = csr_src[p + u * GRP];
    float f[U][8];
#pragma unroll
    for (int u = 0; u < U; ++u) loadH8(f[u], h + (size_t)srcv[u] * HC + c0);
    float wv[U];
#pragma unroll
    for (int u = 0; u < U; ++u) wv[u] = edge_w(as_[srcv[u] * H + head] + adv);
#pragma unroll
    for (int u = 0; u < U; ++u) den += wv[u];
#pragma unroll
    for (int u = 0; u < U; ++u)
#pragma unroll
        for (int i = 0; i < 8; ++i) acc[i] += wv[u] * f[u][i];
}

template<int HC, int H, bool BF16OUT>
__global__ __launch_bounds__(256) void fused_agg(int N,
                                                 const int* __restrict__ row_start,
                                                 const int* __restrict__ csr_src,
                                                 const __half* __restrict__ h,
                                                 const float* __restrict__ as_,
                                                 const float* __restrict__ ad_,
                                                 const float* __restrict__ bias,
                                                 float* __restrict__ out,
                                                 unsigned short* __restrict__ outh,
                                                 unsigned short* __restrict__ outl) {
    constexpr int LPE = HC / 8;          // lanes per edge (32 or 16)
    constexpr int GRP = 64 / LPE;        // concurrent edges per wave (2 or 4)
    constexpr int C = HC / H;
    const int n = blockIdx.x * 4 + (threadIdx.x >> 6);
    if (n >= N) return;
    const int lane = threadIdx.x & 63;
    const int g = lane / LPE;
    const int lq = lane % LPE;
    const int c0 = lq * 8;
    const int head = c0 / C;
    const int s0 = row_start[n], s1 = row_start[n + 1];
    const float adv = ad_[n * H + head];
    float acc[8] = {};
    float den = 0.f;
    int p = s0 + g;
    for (; p + 3 * GRP < s1; p += 4 * GRP)
        agg_step<4, HC, H, GRP>(p, csr_src, h, as_, adv, c0, head, acc, den);
    for (; p < s1; p += GRP)
        agg_step<1, HC, H, GRP>(p, csr_src, h, as_, adv, c0, head, acc, den);
#pragma unroll
    for (int off = LPE; off < 64; off <<= 1) {
        den += __shfl_xor(den, off);
#pragma unroll
        for (int i = 0; i < 8; ++i) acc[i] += __shfl_xor(acc[i], off);
    }
    if (g == 0) {
        float dinv = 1.0f / (den + 1e-16f);
        float o[8];
#pragma unroll
        for (int i = 0; i < 8; ++i) {
            float v = acc[i] * dinv + bias[c0 + i];
            o[i] = v > 0.f ? v : 0.f;
        }
        if (BF16OUT) {
            s16x8 hb, lb;
#pragma unroll
            for (int i = 0; i < 8; ++i) {
                unsigned short hh = f2bf(o[i]);
                hb[i] = (short)hh;
                lb[i] = (short)f2bf(o[i] - bf2f(hh));
            }
            *(s16x8*)(outh + (size_t)n * HC + c0) = hb;
            *(s16x8*)(outl + (size_t)n * HC + c0) = lb;
        } else {
            float4 v0 = make_float4(o[0], o[1], o[2], o[3]);
            float4 v1 = make_float4(o[4], o[5], o[6], o[7]);
            *(float4*)(out + (size_t)n * HC + c0) = v0;
            *(float4*)(out + (size_t)n * HC + c0 + 4) = v1;
        }
    }
}

extern "C" void kernel_launch(void* const* d_in, const int* in_sizes, int n_in,
                              void* d_out, int out_size, void* d_ws, size_t ws_size,
                              hipStream_t stream) {
    const float* x      = (const float*)d_in[0];
    const int*   ei     = (const int*)d_in[1];
    const float* W1     = (const float*)d_in[2];
    const float* att_s1 = (const float*)d_in[3];
    const float* att_d1 = (const float*)d_in[4];
    const float* b1     = (const float*)d_in[5];
    const float* W2     = (const float*)d_in[6];
    const float* att_s2 = (const float*)d_in[7];
    const float* att_d2 = (const float*)d_in[8];
    const float* b2     = (const float*)d_in[9];
    float* out = (float*)d_out;

    const int N_ = in_sizes[0] / 128;   // 50000
    const int E_ = in_sizes[1] / 2;     // 800000
    const int Etot = E_ + N_;           // 850000

    // workspace layout
    __half* h1 = (__half*)d_ws;                              // N*256 fp16 (also h2)
    unsigned short* x2h = (unsigned short*)(h1 + (size_t)N_ * 256);  // N*256 bf16
    unsigned short* x2l = x2h + (size_t)N_ * 256;                    // N*256 bf16
    unsigned short* xh = x2h;                                // N*128 bf16 (overlay)
    unsigned short* xl = x2l;                                // N*128 bf16 (overlay)
    unsigned short* bp1h = x2l + (size_t)N_ * 256;           // 32768
    unsigned short* bp1l = bp1h + 32768;
    unsigned short* bp2h = bp1l + 32768;
    unsigned short* bp2l = bp2h + 32768;
    float* as1 = (float*)(bp2l + 32768);                     // N*4
    float* ad1 = as1 + (size_t)N_ * 4;                       // N*4
    float* as2 = ad1 + (size_t)N_ * 4;                       // N
    float* ad2 = as2 + N_;                                   // N
    int* cnt       = (int*)(ad2 + N_);                       // N
    int* row_start = cnt + N_;                               // N+1
    int* cursor    = row_start + (N_ + 1);                   // N
    int* bsum      = cursor + N_;                            // 256
    int* csr_src   = bsum + 256;                             // Etot

    hipMemsetAsync(cnt, 0, (size_t)N_ * 4, stream);
    hipMemsetAsync(as2, 0, (size_t)N_ * 2 * 4, stream);      // as2+ad2 (atomic targets)

    int eb = (Etot + 255) / 256;
    int nb = (N_ + 255) / 256;          // 196
    count_kernel<<<eb, 256, 0, stream>>>(ei, E_, N_, cnt);
    scan_blocks<<<nb, 256, 0, stream>>>(cnt, row_start, bsum, N_);
    scan_bsums<<<1, 256, 0, stream>>>(bsum, row_start, nb, N_);
    scan_add<<<nb, 256, 0, stream>>>(row_start, bsum, cursor, N_);
    fill_kernel<<<eb, 256, 0, stream>>>(ei, E_, N_, cursor, csr_src);

    split_kernel<<<((N_ * 128) + 255) / 256, 256, 0, stream>>>(x, xh, xl, N_ * 128);
    pack_w<<<(128 * 256 + 255) / 256, 256, 0, stream>>>(W1, bp1h, bp1l, 128, 256);
    pack_w<<<(256 * 128 + 255) / 256, 256, 0, stream>>>(W2, bp2h, bp2l, 256, 128);

    // ---- layer 1: 128 -> 4x64 ----
    mfma_gemm<128, 256, 4, false><<<(N_ + 31) / 32, 256, 0, stream>>>(
        N_, xh, xl, bp1h, bp1l, att_s1, att_d1, as1, ad1, h1);
    fused_agg<256, 4, true><<<(N_ + 3) / 4, 256, 0, stream>>>(
        N_, row_start, csr_src, h1, as1, ad1, b1, nullptr, x2h, x2l);

    // ---- layer 2: 256 -> 1x128 ----
    __half* h2 = h1;  // reuse
    mfma_gemm<256, 128, 1, true><<<(N_ + 63) / 64, 256, 0, stream>>>(
        N_, x2h, x2l, bp2h, bp2l, att_s2, att_d2, as2, ad2, h2);
    fused_agg<128, 1, false><<<(N_ + 3) / 4, 256, 0, stream>>>(
        N_, row_start, csr_src, h2, as2, ad2, b2, out, nullptr, nullptr);

    (void)n_in; (void)out_size; (void)ws_size;
}